// Round 3
// baseline (991.533 us; speedup 1.0000x reference)
//
#include <hip/hip_runtime.h>
#include <hip/hip_bf16.h>

#define DIN 96
#define DOUT 32
#define NH 4
#define DTOT 128          // NH * DOUT, concat output width
#define SLOPE 0.2f
#define NPBF 64           // nodes per block in feat_kernel (4 per thread)

// pack two fp32 -> two bf16 (RNE) in one uint
__device__ __forceinline__ unsigned int packbf2(float lo, float hi) {
    unsigned int a = __float_as_uint(lo), b = __float_as_uint(hi);
    a += 0x7fffu + ((a >> 16) & 1u);
    b += 0x7fffu + ((b >> 16) & 1u);
    return (a >> 16) | (b & 0xffff0000u);
}

// ---------------------------------------------------------------------------
// Kernel A: h[n] = x[n] @ W (all heads) -> packed bf16, plus per-node
// attention exp factors. Also fused: per-src-node degree histogram
// (fire-and-forget global atomics into L2-resident deg[], hidden under FMAs).
//   - 4 nodes/thread (64 nodes/block): 32 FMA per W-fragment read
//   - W split into Wlo/Whi planes -> ds_read_b128 at 16B stride, bank-clean
//   - x read via guarded float4 global loads (L1-resident, wave-broadcast)
// ---------------------------------------------------------------------------
__global__ __launch_bounds__(256) void feat_kernel(
    const float* __restrict__ x, const float* __restrict__ W,
    const float* __restrict__ a, const int* __restrict__ esrc,
    unsigned int* __restrict__ hq,      // [N*64] packed bf16 pairs
    float2* __restrict__ usrc, float2* __restrict__ vdst,
    int* __restrict__ deg, int n_nodes, int n_edges)
{
    __shared__ float Wlo[DIN * 64];     // [k][cbi*4 + jj], cols 8*cbi + jj
    __shared__ float Whi[DIN * 64];     // [k][cbi*4 + jj], cols 8*cbi + 4 + jj
    __shared__ float al[NH * 2 * DOUT];
    const int t = threadIdx.x;

    // ---- fused degree histogram over this block's edge slice ----
    {
        const int nbk = (int)gridDim.x;
        const int epbf = (n_edges + nbk - 1) / nbk;
        const int base = blockIdx.x * epbf;
        const int end = min(base + epbf, n_edges);
        for (int e = base + t; e < end; e += 256)
            atomicAdd(&deg[esrc[e]], 1);
    }

    // stage W: linear read (coalesced), split write into lo/hi planes
    for (int i = t; i < DIN * DTOT; i += 256) {
        int k = i >> 7, c = i & 127;        // c = output col 0..127
        int head = c >> 5, j = c & 31;
        float w = W[head * (DIN * DOUT) + k * DOUT + j];
        int cbi = c >> 3, jj = c & 7;
        if (jj < 4) Wlo[(k << 6) + (cbi << 2) + jj] = w;
        else        Whi[(k << 6) + (cbi << 2) + (jj - 4)] = w;
    }
    for (int i = t; i < NH * 2 * DOUT; i += 256) al[i] = a[i];
    __syncthreads();

    const int cbi = t & 15;             // column block: cols 8*cbi .. 8*cbi+7
    const int ng = t >> 4;              // node group (4 nodes)
    const int node0 = blockIdx.x * NPBF;
    const int g0 = node0 + ng * 4;

    bool ok[4];
    const float* xp[4];
#pragma unroll
    for (int i = 0; i < 4; ++i) {
        ok[i] = (g0 + i) < n_nodes;
        xp[i] = x + (size_t)(g0 + i) * DIN;
    }

    float acc[4][8];
#pragma unroll
    for (int i = 0; i < 4; ++i)
#pragma unroll
        for (int j = 0; j < 8; ++j) acc[i][j] = 0.f;

    for (int k = 0; k < DIN; k += 4) {
        float4 xv[4];
#pragma unroll
        for (int i = 0; i < 4; ++i)
            xv[i] = ok[i] ? *(const float4*)(xp[i] + k)
                          : make_float4(0.f, 0.f, 0.f, 0.f);
#pragma unroll
        for (int kk = 0; kk < 4; ++kk) {
            const float4 wlo = *(const float4*)&Wlo[((k + kk) << 6) + (cbi << 2)];
            const float4 whi = *(const float4*)&Whi[((k + kk) << 6) + (cbi << 2)];
#pragma unroll
            for (int i = 0; i < 4; ++i) {
                const float xvv = (kk == 0) ? xv[i].x : (kk == 1) ? xv[i].y
                                 : (kk == 2) ? xv[i].z : xv[i].w;
                acc[i][0] = fmaf(xvv, wlo.x, acc[i][0]);
                acc[i][1] = fmaf(xvv, wlo.y, acc[i][1]);
                acc[i][2] = fmaf(xvv, wlo.z, acc[i][2]);
                acc[i][3] = fmaf(xvv, wlo.w, acc[i][3]);
                acc[i][4] = fmaf(xvv, whi.x, acc[i][4]);
                acc[i][5] = fmaf(xvv, whi.y, acc[i][5]);
                acc[i][6] = fmaf(xvv, whi.z, acc[i][6]);
                acc[i][7] = fmaf(xvv, whi.w, acc[i][7]);
            }
        }
    }

    const int head = cbi >> 2;
    const int j0 = (cbi & 3) << 3;
#pragma unroll
    for (int i = 0; i < 4; ++i) {
        float ps = 0.f, pd = 0.f;
#pragma unroll
        for (int j = 0; j < 8; ++j) {
            ps += acc[i][j] * al[head * 64 + j0 + j];
            pd += acc[i][j] * al[head * 64 + 32 + j0 + j];
        }
        ps += __shfl_xor(ps, 1); ps += __shfl_xor(ps, 2);
        pd += __shfl_xor(pd, 1); pd += __shfl_xor(pd, 2);
        const int g = g0 + i;
        if (ok[i]) {
            uint4 pk;
            pk.x = packbf2(acc[i][0], acc[i][1]);
            pk.y = packbf2(acc[i][2], acc[i][3]);
            pk.z = packbf2(acc[i][4], acc[i][5]);
            pk.w = packbf2(acc[i][6], acc[i][7]);
            *(uint4*)&hq[(size_t)g * 64 + (cbi << 2)] = pk;
            if ((cbi & 3) == 0) {
                usrc[g * NH + head] = make_float2(__expf(-ps), __expf(-SLOPE * ps));
                vdst[g * NH + head] = make_float2(__expf(-pd), __expf(-SLOPE * pd));
            }
        }
    }
}

// ---------------------------------------------------------------------------
// Single-block scan: offs[n] = exclusive prefix of 4-padded deg; cur = copy.
// 1024 threads, each owns a contiguous chunk of ~(N/1024) nodes.
// ---------------------------------------------------------------------------
__global__ __launch_bounds__(1024) void scan_kernel(
    const int* __restrict__ deg, int* __restrict__ offs,
    int* __restrict__ cur, int n_nodes)
{
    __shared__ int tmp[1024];
    const int t = threadIdx.x;
    const int C = (n_nodes + 1023) >> 10;
    const int lo = t * C;
    const int hi = min(lo + C, n_nodes);
    int sum = 0;
    for (int n = lo; n < hi; ++n) sum += (deg[n] + 3) & ~3;
    tmp[t] = sum;
    __syncthreads();
    for (int off = 1; off < 1024; off <<= 1) {
        int v = (t >= off) ? tmp[t - off] : 0;
        __syncthreads();
        tmp[t] += v;
        __syncthreads();
    }
    int run = tmp[t] - sum;  // exclusive prefix for this thread's chunk
    for (int n = lo; n < hi; ++n) {
        offs[n] = run;
        cur[n] = run;
        run += (deg[n] + 3) & ~3;
    }
}

// ---------------------------------------------------------------------------
// Scatter: direct CSR build. pos = atomicAdd(cur[src]); slots[pos] = dst.
// cur[] is 400KB -> L2-resident; random src -> negligible same-address
// contention. int4 edge loads (16B/lane), grid-stride.
// Within-node order is arbitrary (same numerics class as the old racing
// LDS-cursor sort).
// ---------------------------------------------------------------------------
__global__ __launch_bounds__(256) void scatter_kernel(
    const int* __restrict__ esrc, const int* __restrict__ edst,
    int* __restrict__ cur, int* __restrict__ slots, int n_edges)
{
    const int nb4 = n_edges >> 2;
    const int tid = blockIdx.x * 256 + threadIdx.x;
    const int stride = gridDim.x * 256;
    for (int i = tid; i < nb4; i += stride) {
        int4 s4 = ((const int4*)esrc)[i];
        int4 d4 = ((const int4*)edst)[i];
        int p0 = atomicAdd(&cur[s4.x], 1);
        int p1 = atomicAdd(&cur[s4.y], 1);
        int p2 = atomicAdd(&cur[s4.z], 1);
        int p3 = atomicAdd(&cur[s4.w], 1);
        slots[p0] = d4.x;
        slots[p1] = d4.y;
        slots[p2] = d4.z;
        slots[p3] = d4.w;
    }
    for (int e = (nb4 << 2) + tid; e < n_edges; e += stride) {
        int p = atomicAdd(&cur[esrc[e]], 1);
        slots[p] = edst[e];
    }
}

// ---------------------------------------------------------------------------
// Gather: 64 lanes per node, 2 cols per lane (bf16x2 h loads).
// 32-bit byte-offset addressing + 2-stage software pipeline.
// (Unchanged: sits on the scattered-256B-row HBM/L3 path ceiling,
//  ~163 us / FETCH 500 MB stable across rounds.)
// ---------------------------------------------------------------------------
__global__ __launch_bounds__(256) void gather_kernel(
    const int* __restrict__ slots, const int* __restrict__ offsets,
    const int* __restrict__ deg,
    const unsigned int* __restrict__ hv,    // [N*64] packed bf16 pairs
    const float2* __restrict__ usrc, const float2* __restrict__ vdst,
    float* __restrict__ out, int n_nodes)
{
    const int t = threadIdx.x;
    const int node = blockIdx.x * 4 + (t >> 6);
    if (node >= n_nodes) return;
    const int l = t & 63;          // cols {2l, 2l+1}
    const int head = l >> 4;
    const unsigned loff = (unsigned)l << 2;     // byte offset within hv row (256B)
    const unsigned hoff = (unsigned)head << 3;  // byte offset within vdst row (32B)
    const char* __restrict__ hvb = (const char*)hv;
    const char* __restrict__ vdb = (const char*)vdst;
    const float2 u = usrc[(unsigned)node * 4u + head];
    const int beg = offsets[node]; // multiple of 4
    const int d = deg[node];

    float ax0 = 0.f, ay0 = 0.f, ax1 = 0.f, ay1 = 0.f;
    float ax2 = 0.f, ay2 = 0.f, ax3 = 0.f, ay3 = 0.f;

#define LDV(c) (*(const float2*)(vdb + ((((unsigned)(c)) << 5) + hoff)))
#define LDW(c) (*(const unsigned int*)(hvb + ((((unsigned)(c)) << 8) + loff)))
#define COMP(vv, ww, AX, AY) do {                                   \
        float e_ = fminf(u.x * (vv).x, u.y * (vv).y);               \
        AX = fmaf(e_, __uint_as_float((ww) << 16), AX);             \
        AY = fmaf(e_, __uint_as_float((ww) & 0xffff0000u), AY);     \
    } while (0)

    int k = 0;
    if (d >= 4) {
        int4 cA = *(const int4*)(slots + beg);
        float2 vA0 = LDV(cA.x), vA1 = LDV(cA.y), vA2 = LDV(cA.z), vA3 = LDV(cA.w);
        unsigned wA0 = LDW(cA.x), wA1 = LDW(cA.y), wA2 = LDW(cA.z), wA3 = LDW(cA.w);

        for (; k + 12 <= d; k += 8) {
            int4 cB = *(const int4*)(slots + beg + k + 4);
            float2 vB0 = LDV(cB.x), vB1 = LDV(cB.y), vB2 = LDV(cB.z), vB3 = LDV(cB.w);
            unsigned wB0 = LDW(cB.x), wB1 = LDW(cB.y), wB2 = LDW(cB.z), wB3 = LDW(cB.w);
            COMP(vA0, wA0, ax0, ay0); COMP(vA1, wA1, ax1, ay1);
            COMP(vA2, wA2, ax2, ay2); COMP(vA3, wA3, ax3, ay3);
            int4 cN = *(const int4*)(slots + beg + k + 8);
            vA0 = LDV(cN.x); vA1 = LDV(cN.y); vA2 = LDV(cN.z); vA3 = LDV(cN.w);
            wA0 = LDW(cN.x); wA1 = LDW(cN.y); wA2 = LDW(cN.z); wA3 = LDW(cN.w);
            COMP(vB0, wB0, ax0, ay0); COMP(vB1, wB1, ax1, ay1);
            COMP(vB2, wB2, ax2, ay2); COMP(vB3, wB3, ax3, ay3);
        }
        if (k + 8 <= d) {
            int4 cB = *(const int4*)(slots + beg + k + 4);
            float2 vB0 = LDV(cB.x), vB1 = LDV(cB.y), vB2 = LDV(cB.z), vB3 = LDV(cB.w);
            unsigned wB0 = LDW(cB.x), wB1 = LDW(cB.y), wB2 = LDW(cB.z), wB3 = LDW(cB.w);
            COMP(vA0, wA0, ax0, ay0); COMP(vA1, wA1, ax1, ay1);
            COMP(vA2, wA2, ax2, ay2); COMP(vA3, wA3, ax3, ay3);
            COMP(vB0, wB0, ax0, ay0); COMP(vB1, wB1, ax1, ay1);
            COMP(vB2, wB2, ax2, ay2); COMP(vB3, wB3, ax3, ay3);
            k += 8;
        } else {
            COMP(vA0, wA0, ax0, ay0); COMP(vA1, wA1, ax1, ay1);
            COMP(vA2, wA2, ax2, ay2); COMP(vA3, wA3, ax3, ay3);
            k += 4;
        }
    }
    for (; k < d; ++k) {
        int c = slots[beg + k];
        float2 v = LDV(c);
        unsigned w = LDW(c);
        COMP(v, w, ax0, ay0);
    }
#undef LDV
#undef LDW
#undef COMP

    float rx = (ax0 + ax1) + (ax2 + ax3);
    float ry = (ay0 + ay1) + (ay2 + ay3);
    rx = rx > 0.f ? rx : __expf(rx) - 1.f;
    ry = ry > 0.f ? ry : __expf(ry) - 1.f;
    ((float2*)out)[(unsigned)node * 64u + l] = make_float2(rx, ry);
}

extern "C" void kernel_launch(void* const* d_in, const int* in_sizes, int n_in,
                              void* d_out, int out_size, void* d_ws, size_t ws_size,
                              hipStream_t stream)
{
    const float* x  = (const float*)d_in[0];
    const float* W  = (const float*)d_in[1];
    const float* a  = (const float*)d_in[2];
    const int* esrc = (const int*)d_in[3];
    const int* edst = (const int*)d_in[4];
    const int n_nodes = in_sizes[0] / DIN;
    const int n_edges = in_sizes[3];
    float* out = (float*)d_out;

    // workspace layout
    unsigned int* hq = (unsigned int*)d_ws;                 // [N*64] bf16 pairs, 25.6MB
    float2* usrc = (float2*)(hq + (size_t)n_nodes * 64);    // [N*4]
    float2* vdst = usrc + (size_t)n_nodes * NH;             // [N*4]
    int* offs   = (int*)(vdst + (size_t)n_nodes * NH);      // [N]
    int* deg    = offs + n_nodes;                           // [N]
    int* cur    = deg + n_nodes;                            // [N]
    int* slots  = cur + n_nodes;                            // [E + 3N + 64]

    hipMemsetAsync(deg, 0, (size_t)n_nodes * sizeof(int), stream);

    feat_kernel<<<(n_nodes + NPBF - 1) / NPBF, 256, 0, stream>>>(
        x, W, a, esrc, hq, usrc, vdst, deg, n_nodes, n_edges);

    scan_kernel<<<1, 1024, 0, stream>>>(deg, offs, cur, n_nodes);

    const int nb4 = n_edges >> 2;
    int sblocks = (nb4 + 255) / 256;
    if (sblocks > 4096) sblocks = 4096;
    if (sblocks < 1) sblocks = 1;
    scatter_kernel<<<sblocks, 256, 0, stream>>>(esrc, edst, cur, slots, n_edges);

    gather_kernel<<<(n_nodes + 3) / 4, 256, 0, stream>>>(
        slots, offs, deg, hq, usrc, vdst, out, n_nodes);
}

// Round 4
// 471.146 us; speedup vs baseline: 2.1045x; 2.1045x over previous
//
#include <hip/hip_runtime.h>
#include <hip/hip_bf16.h>

#define DIN 96
#define DOUT 32
#define NH 4
#define DTOT 128          // NH * DOUT, concat output width
#define SLOPE 0.2f
#define NPBF 64           // nodes per block in feat_kernel (4 per thread)
#define BSH 7             // bucket shift: 128 src nodes per bucket
#define BNODES 128
#define MAXB 1024         // max buckets (N <= 131072)
#define EPB 4096          // edges per block in binscatter (782 blocks, 3/CU)

// pack two fp32 -> two bf16 (RNE) in one uint
__device__ __forceinline__ unsigned int packbf2(float lo, float hi) {
    unsigned int a = __float_as_uint(lo), b = __float_as_uint(hi);
    a += 0x7fffu + ((a >> 16) & 1u);
    b += 0x7fffu + ((b >> 16) & 1u);
    return (a >> 16) | (b & 0xffff0000u);
}

// ---------------------------------------------------------------------------
// Kernel A: h[n] = x[n] @ W (all heads) -> packed bf16, plus per-node
// attention exp factors. Fused: coarse-bucket edge histogram (replaces the
// former bincount kernel): LDS hist over ~2048 edges/block, one global
// atomic flush per nonempty bucket.
// ---------------------------------------------------------------------------
__global__ __launch_bounds__(256) void feat_kernel(
    const float* __restrict__ x, const float* __restrict__ W,
    const float* __restrict__ a, const int* __restrict__ esrc,
    unsigned int* __restrict__ hq,      // [N*64] packed bf16 pairs
    float2* __restrict__ usrc, float2* __restrict__ vdst,
    int* __restrict__ counts, int n_nodes, int n_edges, int nb)
{
    __shared__ float Wlo[DIN * 64];     // [k][cbi*4 + jj], cols 8*cbi + jj
    __shared__ float Whi[DIN * 64];     // [k][cbi*4 + jj], cols 8*cbi + 4 + jj
    __shared__ float al[NH * 2 * DOUT];
    __shared__ int bch[MAXB];
    const int t = threadIdx.x;

    // stage W: linear read (coalesced), split write into lo/hi planes
    for (int i = t; i < DIN * DTOT; i += 256) {
        int k = i >> 7, c = i & 127;        // c = output col 0..127
        int head = c >> 5, j = c & 31;
        float w = W[head * (DIN * DOUT) + k * DOUT + j];
        int cbi = c >> 3, jj = c & 7;
        if (jj < 4) Wlo[(k << 6) + (cbi << 2) + jj] = w;
        else        Whi[(k << 6) + (cbi << 2) + (jj - 4)] = w;
    }
    for (int i = t; i < NH * 2 * DOUT; i += 256) al[i] = a[i];
    for (int i = t; i < MAXB; i += 256) bch[i] = 0;
    __syncthreads();

    // ---- fused coarse-bucket histogram over this block's edge slice ----
    {
        const int nbk = (int)gridDim.x;
        const int epbf = (n_edges + nbk - 1) / nbk;
        const int base = blockIdx.x * epbf;
        const int end = min(base + epbf, n_edges);
        for (int e = base + t; e < end; e += 256)
            atomicAdd(&bch[esrc[e] >> BSH], 1);
    }
    __syncthreads();
    for (int i = t; i < nb; i += 256)
        if (bch[i] > 0) atomicAdd(&counts[i], bch[i]);
    // no sync needed: bch not reused; Wlo/Whi were synced above

    const int cbi = t & 15;             // column block: cols 8*cbi .. 8*cbi+7
    const int ng = t >> 4;              // node group (4 nodes)
    const int node0 = blockIdx.x * NPBF;
    const int g0 = node0 + ng * 4;

    bool ok[4];
    const float* xp[4];
#pragma unroll
    for (int i = 0; i < 4; ++i) {
        ok[i] = (g0 + i) < n_nodes;
        xp[i] = x + (size_t)(g0 + i) * DIN;
    }

    float acc[4][8];
#pragma unroll
    for (int i = 0; i < 4; ++i)
#pragma unroll
        for (int j = 0; j < 8; ++j) acc[i][j] = 0.f;

    for (int k = 0; k < DIN; k += 4) {
        float4 xv[4];
#pragma unroll
        for (int i = 0; i < 4; ++i)
            xv[i] = ok[i] ? *(const float4*)(xp[i] + k)
                          : make_float4(0.f, 0.f, 0.f, 0.f);
#pragma unroll
        for (int kk = 0; kk < 4; ++kk) {
            const float4 wlo = *(const float4*)&Wlo[((k + kk) << 6) + (cbi << 2)];
            const float4 whi = *(const float4*)&Whi[((k + kk) << 6) + (cbi << 2)];
#pragma unroll
            for (int i = 0; i < 4; ++i) {
                const float xvv = (kk == 0) ? xv[i].x : (kk == 1) ? xv[i].y
                                 : (kk == 2) ? xv[i].z : xv[i].w;
                acc[i][0] = fmaf(xvv, wlo.x, acc[i][0]);
                acc[i][1] = fmaf(xvv, wlo.y, acc[i][1]);
                acc[i][2] = fmaf(xvv, wlo.z, acc[i][2]);
                acc[i][3] = fmaf(xvv, wlo.w, acc[i][3]);
                acc[i][4] = fmaf(xvv, whi.x, acc[i][4]);
                acc[i][5] = fmaf(xvv, whi.y, acc[i][5]);
                acc[i][6] = fmaf(xvv, whi.z, acc[i][6]);
                acc[i][7] = fmaf(xvv, whi.w, acc[i][7]);
            }
        }
    }

    const int head = cbi >> 2;
    const int j0 = (cbi & 3) << 3;
#pragma unroll
    for (int i = 0; i < 4; ++i) {
        float ps = 0.f, pd = 0.f;
#pragma unroll
        for (int j = 0; j < 8; ++j) {
            ps += acc[i][j] * al[head * 64 + j0 + j];
            pd += acc[i][j] * al[head * 64 + 32 + j0 + j];
        }
        ps += __shfl_xor(ps, 1); ps += __shfl_xor(ps, 2);
        pd += __shfl_xor(pd, 1); pd += __shfl_xor(pd, 2);
        const int g = g0 + i;
        if (ok[i]) {
            uint4 pk;
            pk.x = packbf2(acc[i][0], acc[i][1]);
            pk.y = packbf2(acc[i][2], acc[i][3]);
            pk.z = packbf2(acc[i][4], acc[i][5]);
            pk.w = packbf2(acc[i][6], acc[i][7]);
            *(uint4*)&hq[(size_t)g * 64 + (cbi << 2)] = pk;
            if ((cbi & 3) == 0) {
                usrc[g * NH + head] = make_float2(__expf(-ps), __expf(-SLOPE * ps));
                vdst[g * NH + head] = make_float2(__expf(-pd), __expf(-SLOPE * pd));
            }
        }
    }
}

// ---------------------------------------------------------------------------
// scan buckets: bbase (binned layout), gcur (reservation cursor),
// sbase (4-aligned slots layout with +512 pad slack per bucket)
// ---------------------------------------------------------------------------
__global__ __launch_bounds__(1024) void bscan_kernel(
    const int* __restrict__ counts, int* __restrict__ bbase,
    int* __restrict__ gcur, int* __restrict__ sbase, int nb)
{
    __shared__ int tmp[1024];
    const int t = threadIdx.x;
    int v = (t < nb) ? counts[t] : 0;
    tmp[t] = v;
    __syncthreads();
    for (int off = 1; off < 1024; off <<= 1) {
        int xv = (t >= off) ? tmp[t - off] : 0;
        __syncthreads();
        tmp[t] += xv;
        __syncthreads();
    }
    if (t < nb) {
        int excl = tmp[t] - v;
        bbase[t] = excl;
        gcur[t] = excl;
        sbase[t] = ((excl + 3) & ~3) + t * (4 * BNODES);
    }
}

// ---------------------------------------------------------------------------
// Scatter edges (packed srcl|dst) into coarse bucket regions.
// v2: EPB=4096 (782 blocks, 3/CU -> 12 waves/CU latency hiding), edges
// cached in registers (16/thread, static-indexed) -> esrc/edst read ONCE,
// histogram and scatter passes both run from registers with 16-way MLP.
// ---------------------------------------------------------------------------
__global__ __launch_bounds__(256) void binscatter_kernel(
    const int* __restrict__ esrc, const int* __restrict__ edst,
    int* __restrict__ gcur, unsigned int* __restrict__ binned,
    int n_edges, int nb)
{
    __shared__ int bc[MAXB];
    const int t = threadIdx.x;
    for (int i = t; i < nb; i += 256) bc[i] = 0;
    __syncthreads();

    const int base = blockIdx.x * EPB;
    const int end = min(base + EPB, n_edges);
    const bool full = (end - base) == EPB;

    int se[16], de[16];
    if (full) {
        const int4* s4p = (const int4*)(esrc + base);
        const int4* d4p = (const int4*)(edst + base);
#pragma unroll
        for (int j = 0; j < 4; ++j) {
            int4 s4 = s4p[j * 256 + t];
            int4 d4 = d4p[j * 256 + t];
            se[j * 4 + 0] = s4.x; se[j * 4 + 1] = s4.y;
            se[j * 4 + 2] = s4.z; se[j * 4 + 3] = s4.w;
            de[j * 4 + 0] = d4.x; de[j * 4 + 1] = d4.y;
            de[j * 4 + 2] = d4.z; de[j * 4 + 3] = d4.w;
        }
#pragma unroll
        for (int j = 0; j < 16; ++j)
            atomicAdd(&bc[se[j] >> BSH], 1);
    } else {
#pragma unroll
        for (int j = 0; j < 16; ++j) {
            const int e = base + j * 256 + t;
            se[j] = (e < end) ? esrc[e] : 0;
            de[j] = (e < end) ? edst[e] : 0;
            if (e < end) atomicAdd(&bc[se[j] >> BSH], 1);
        }
    }
    __syncthreads();

    // reserve a run per non-empty bucket; bc becomes the running cursor
    for (int i = t; i < nb; i += 256) {
        int c = bc[i];
        bc[i] = (c > 0) ? atomicAdd(&gcur[i], c) : 0;
    }
    __syncthreads();

    if (full) {
#pragma unroll
        for (int j = 0; j < 16; ++j) {
            int s = se[j];
            int pos = atomicAdd(&bc[s >> BSH], 1);
            binned[pos] = ((unsigned int)(s & (BNODES - 1)) << 17) | (unsigned int)de[j];
        }
    } else {
#pragma unroll
        for (int j = 0; j < 16; ++j) {
            const int e = base + j * 256 + t;
            if (e < end) {
                int s = se[j];
                int pos = atomicAdd(&bc[s >> BSH], 1);
                binned[pos] = ((unsigned int)(s & (BNODES - 1)) << 17) | (unsigned int)de[j];
            }
        }
    }
}

// per-bucket fine sort: LDS per-node hist + scan, write offs/deg and slots
__global__ __launch_bounds__(256) void binfine_kernel(
    const unsigned int* __restrict__ binned,
    const int* __restrict__ counts, const int* __restrict__ bbase,
    const int* __restrict__ sbase,
    int* __restrict__ offs, int* __restrict__ deg,
    int* __restrict__ slots, int n_nodes)
{
    __shared__ int dcnt[BNODES];
    __shared__ int sc[BNODES];
    __shared__ int dcur[BNODES];
    const int t = threadIdx.x;
    const int b = blockIdx.x;
    const int cnt = counts[b];
    const int start = bbase[b];
    const int sb = sbase[b];
    const int node0 = b << BSH;

    if (t < BNODES) dcnt[t] = 0;
    __syncthreads();
    for (int i = t; i < cnt; i += 256)
        atomicAdd(&dcnt[binned[start + i] >> 17], 1);
    __syncthreads();
    int pd = 0;
    if (t < BNODES) { pd = (dcnt[t] + 3) & ~3; sc[t] = pd; }
    __syncthreads();
    for (int off = 1; off < BNODES; off <<= 1) {
        int v = 0;
        if (t < BNODES && t >= off) v = sc[t - off];
        __syncthreads();
        if (t < BNODES) sc[t] += v;
        __syncthreads();
    }
    if (t < BNODES) {
        int o = sb + sc[t] - pd;   // 4-aligned per-node start
        dcur[t] = o;
        int node = node0 + t;
        if (node < n_nodes) { offs[node] = o; deg[node] = dcnt[t]; }
    }
    __syncthreads();
    for (int i = t; i < cnt; i += 256) {
        unsigned int w = binned[start + i];
        int pos = atomicAdd(&dcur[w >> 17], 1);
        slots[pos] = (int)(w & 0x1ffffu);
    }
}

// ---------------------------------------------------------------------------
// Gather: 64 lanes per node, 2 cols per lane (bf16x2 h loads).
// 32-bit byte-offset addressing + 2-stage software pipeline.
// (Unchanged: sits on the scattered-256B-row HBM/L3 path ceiling,
//  ~163 us / FETCH 500 MB stable across rounds.)
// ---------------------------------------------------------------------------
__global__ __launch_bounds__(256) void gather_kernel(
    const int* __restrict__ slots, const int* __restrict__ offsets,
    const int* __restrict__ deg,
    const unsigned int* __restrict__ hv,    // [N*64] packed bf16 pairs
    const float2* __restrict__ usrc, const float2* __restrict__ vdst,
    float* __restrict__ out, int n_nodes)
{
    const int t = threadIdx.x;
    const int node = blockIdx.x * 4 + (t >> 6);
    if (node >= n_nodes) return;
    const int l = t & 63;          // cols {2l, 2l+1}
    const int head = l >> 4;
    const unsigned loff = (unsigned)l << 2;     // byte offset within hv row (256B)
    const unsigned hoff = (unsigned)head << 3;  // byte offset within vdst row (32B)
    const char* __restrict__ hvb = (const char*)hv;
    const char* __restrict__ vdb = (const char*)vdst;
    const float2 u = usrc[(unsigned)node * 4u + head];
    const int beg = offsets[node]; // multiple of 4
    const int d = deg[node];

    float ax0 = 0.f, ay0 = 0.f, ax1 = 0.f, ay1 = 0.f;
    float ax2 = 0.f, ay2 = 0.f, ax3 = 0.f, ay3 = 0.f;

#define LDV(c) (*(const float2*)(vdb + ((((unsigned)(c)) << 5) + hoff)))
#define LDW(c) (*(const unsigned int*)(hvb + ((((unsigned)(c)) << 8) + loff)))
#define COMP(vv, ww, AX, AY) do {                                   \
        float e_ = fminf(u.x * (vv).x, u.y * (vv).y);               \
        AX = fmaf(e_, __uint_as_float((ww) << 16), AX);             \
        AY = fmaf(e_, __uint_as_float((ww) & 0xffff0000u), AY);     \
    } while (0)

    int k = 0;
    if (d >= 4) {
        int4 cA = *(const int4*)(slots + beg);
        float2 vA0 = LDV(cA.x), vA1 = LDV(cA.y), vA2 = LDV(cA.z), vA3 = LDV(cA.w);
        unsigned wA0 = LDW(cA.x), wA1 = LDW(cA.y), wA2 = LDW(cA.z), wA3 = LDW(cA.w);

        for (; k + 12 <= d; k += 8) {
            int4 cB = *(const int4*)(slots + beg + k + 4);
            float2 vB0 = LDV(cB.x), vB1 = LDV(cB.y), vB2 = LDV(cB.z), vB3 = LDV(cB.w);
            unsigned wB0 = LDW(cB.x), wB1 = LDW(cB.y), wB2 = LDW(cB.z), wB3 = LDW(cB.w);
            COMP(vA0, wA0, ax0, ay0); COMP(vA1, wA1, ax1, ay1);
            COMP(vA2, wA2, ax2, ay2); COMP(vA3, wA3, ax3, ay3);
            int4 cN = *(const int4*)(slots + beg + k + 8);
            vA0 = LDV(cN.x); vA1 = LDV(cN.y); vA2 = LDV(cN.z); vA3 = LDV(cN.w);
            wA0 = LDW(cN.x); wA1 = LDW(cN.y); wA2 = LDW(cN.z); wA3 = LDW(cN.w);
            COMP(vB0, wB0, ax0, ay0); COMP(vB1, wB1, ax1, ay1);
            COMP(vB2, wB2, ax2, ay2); COMP(vB3, wB3, ax3, ay3);
        }
        if (k + 8 <= d) {
            int4 cB = *(const int4*)(slots + beg + k + 4);
            float2 vB0 = LDV(cB.x), vB1 = LDV(cB.y), vB2 = LDV(cB.z), vB3 = LDV(cB.w);
            unsigned wB0 = LDW(cB.x), wB1 = LDW(cB.y), wB2 = LDW(cB.z), wB3 = LDW(cB.w);
            COMP(vA0, wA0, ax0, ay0); COMP(vA1, wA1, ax1, ay1);
            COMP(vA2, wA2, ax2, ay2); COMP(vA3, wA3, ax3, ay3);
            COMP(vB0, wB0, ax0, ay0); COMP(vB1, wB1, ax1, ay1);
            COMP(vB2, wB2, ax2, ay2); COMP(vB3, wB3, ax3, ay3);
            k += 8;
        } else {
            COMP(vA0, wA0, ax0, ay0); COMP(vA1, wA1, ax1, ay1);
            COMP(vA2, wA2, ax2, ay2); COMP(vA3, wA3, ax3, ay3);
            k += 4;
        }
    }
    for (; k < d; ++k) {
        int c = slots[beg + k];
        float2 v = LDV(c);
        unsigned w = LDW(c);
        COMP(v, w, ax0, ay0);
    }
#undef LDV
#undef LDW
#undef COMP

    float rx = (ax0 + ax1) + (ax2 + ax3);
    float ry = (ay0 + ay1) + (ay2 + ay3);
    rx = rx > 0.f ? rx : __expf(rx) - 1.f;
    ry = ry > 0.f ? ry : __expf(ry) - 1.f;
    ((float2*)out)[(unsigned)node * 64u + l] = make_float2(rx, ry);
}

extern "C" void kernel_launch(void* const* d_in, const int* in_sizes, int n_in,
                              void* d_out, int out_size, void* d_ws, size_t ws_size,
                              hipStream_t stream)
{
    const float* x  = (const float*)d_in[0];
    const float* W  = (const float*)d_in[1];
    const float* a  = (const float*)d_in[2];
    const int* esrc = (const int*)d_in[3];
    const int* edst = (const int*)d_in[4];
    const int n_nodes = in_sizes[0] / DIN;
    const int n_edges = in_sizes[3];
    float* out = (float*)d_out;

    const int nb = (n_nodes + BNODES - 1) >> BSH;

    // workspace layout
    unsigned int* hq = (unsigned int*)d_ws;                 // [N*64] bf16 pairs, 25.6MB
    float2* usrc = (float2*)(hq + (size_t)n_nodes * 64);    // [N*4]
    float2* vdst = usrc + (size_t)n_nodes * NH;             // [N*4]
    int* offs   = (int*)(vdst + (size_t)n_nodes * NH);      // [N]
    int* deg    = offs + n_nodes;                           // [N]
    int* counts = deg + n_nodes;                            // [MAXB]
    int* bbase  = counts + MAXB;                            // [MAXB]
    int* gcur   = bbase + MAXB;                             // [MAXB]
    int* sbase  = gcur + MAXB;                              // [MAXB]
    unsigned int* binned = (unsigned int*)(sbase + MAXB);   // [E]
    int* slots  = (int*)(binned + n_edges);                 // [E + 512*nb + 64]

    hipMemsetAsync(counts, 0, MAXB * sizeof(int), stream);

    feat_kernel<<<(n_nodes + NPBF - 1) / NPBF, 256, 0, stream>>>(
        x, W, a, esrc, hq, usrc, vdst, counts, n_nodes, n_edges, nb);

    bscan_kernel<<<1, 1024, 0, stream>>>(counts, bbase, gcur, sbase, nb);

    binscatter_kernel<<<(n_edges + EPB - 1) / EPB, 256, 0, stream>>>(
        esrc, edst, gcur, binned, n_edges, nb);

    binfine_kernel<<<nb, 256, 0, stream>>>(
        binned, counts, bbase, sbase, offs, deg, slots, n_nodes);

    gather_kernel<<<(n_nodes + 3) / 4, 256, 0, stream>>>(
        slots, offs, deg, hq, usrc, vdst, out, n_nodes);
}

// Round 5
// 423.326 us; speedup vs baseline: 2.3422x; 1.1130x over previous
//
#include <hip/hip_runtime.h>
#include <hip/hip_bf16.h>

#define DIN 96
#define DOUT 32
#define NH 4
#define DTOT 128          // NH * DOUT, concat output width
#define SLOPE 0.2f
#define NPBF 64           // nodes per block in feat_kernel (4 per thread)
#define BSH 7             // bucket shift: 128 src nodes per bucket
#define BNODES 128
#define MAXB 1024         // max buckets (N <= 131072)
#define EPB 4096          // edges per block in binscatter (782 blocks, 3/CU)
#define BCAP 5632         // fixed bucket capacity: E/nb=4096 avg, +24 sigma;
                          // also >= maxcnt + 512 pad for 4-aligned node slots

// pack two fp32 -> two bf16 (RNE) in one uint
__device__ __forceinline__ unsigned int packbf2(float lo, float hi) {
    unsigned int a = __float_as_uint(lo), b = __float_as_uint(hi);
    a += 0x7fffu + ((a >> 16) & 1u);
    b += 0x7fffu + ((b >> 16) & 1u);
    return (a >> 16) | (b & 0xffff0000u);
}

// ---------------------------------------------------------------------------
// Kernel A (fast R2 form): h[n] = x[n] @ W (all heads) -> packed bf16, plus
// per-node attention exp factors. Block 0 also initializes the bucket
// reservation cursors gcur[b] = b*BCAP (replaces memset+bincount+bscan).
//   - 4 nodes/thread (64 nodes/block): 32 FMA per W-fragment read
//   - W split into Wlo/Whi planes -> ds_read_b128 at 16B stride, bank-clean
//   - 50 KB LDS -> 3 blocks/CU
// ---------------------------------------------------------------------------
__global__ __launch_bounds__(256) void feat_kernel(
    const float* __restrict__ x, const float* __restrict__ W,
    const float* __restrict__ a,
    unsigned int* __restrict__ hq,      // [N*64] packed bf16 pairs
    float2* __restrict__ usrc, float2* __restrict__ vdst,
    int* __restrict__ gcur, int n_nodes, int nb)
{
    __shared__ float Wlo[DIN * 64];     // [k][cbi*4 + jj], cols 8*cbi + jj
    __shared__ float Whi[DIN * 64];     // [k][cbi*4 + jj], cols 8*cbi + 4 + jj
    __shared__ float al[NH * 2 * DOUT];
    const int t = threadIdx.x;

    if (blockIdx.x == 0)
        for (int i = t; i < nb; i += 256) gcur[i] = i * BCAP;

    // stage W: linear read (coalesced), split write into lo/hi planes
    for (int i = t; i < DIN * DTOT; i += 256) {
        int k = i >> 7, c = i & 127;        // c = output col 0..127
        int head = c >> 5, j = c & 31;
        float w = W[head * (DIN * DOUT) + k * DOUT + j];
        int cbi = c >> 3, jj = c & 7;
        if (jj < 4) Wlo[(k << 6) + (cbi << 2) + jj] = w;
        else        Whi[(k << 6) + (cbi << 2) + (jj - 4)] = w;
    }
    for (int i = t; i < NH * 2 * DOUT; i += 256) al[i] = a[i];
    __syncthreads();

    const int cbi = t & 15;             // column block: cols 8*cbi .. 8*cbi+7
    const int ng = t >> 4;              // node group (4 nodes)
    const int node0 = blockIdx.x * NPBF;
    const int g0 = node0 + ng * 4;

    bool ok[4];
    const float* xp[4];
#pragma unroll
    for (int i = 0; i < 4; ++i) {
        ok[i] = (g0 + i) < n_nodes;
        xp[i] = x + (size_t)(g0 + i) * DIN;
    }

    float acc[4][8];
#pragma unroll
    for (int i = 0; i < 4; ++i)
#pragma unroll
        for (int j = 0; j < 8; ++j) acc[i][j] = 0.f;

    for (int k = 0; k < DIN; k += 4) {
        float4 xv[4];
#pragma unroll
        for (int i = 0; i < 4; ++i)
            xv[i] = ok[i] ? *(const float4*)(xp[i] + k)
                          : make_float4(0.f, 0.f, 0.f, 0.f);
#pragma unroll
        for (int kk = 0; kk < 4; ++kk) {
            const float4 wlo = *(const float4*)&Wlo[((k + kk) << 6) + (cbi << 2)];
            const float4 whi = *(const float4*)&Whi[((k + kk) << 6) + (cbi << 2)];
#pragma unroll
            for (int i = 0; i < 4; ++i) {
                const float xvv = (kk == 0) ? xv[i].x : (kk == 1) ? xv[i].y
                                 : (kk == 2) ? xv[i].z : xv[i].w;
                acc[i][0] = fmaf(xvv, wlo.x, acc[i][0]);
                acc[i][1] = fmaf(xvv, wlo.y, acc[i][1]);
                acc[i][2] = fmaf(xvv, wlo.z, acc[i][2]);
                acc[i][3] = fmaf(xvv, wlo.w, acc[i][3]);
                acc[i][4] = fmaf(xvv, whi.x, acc[i][4]);
                acc[i][5] = fmaf(xvv, whi.y, acc[i][5]);
                acc[i][6] = fmaf(xvv, whi.z, acc[i][6]);
                acc[i][7] = fmaf(xvv, whi.w, acc[i][7]);
            }
        }
    }

    const int head = cbi >> 2;
    const int j0 = (cbi & 3) << 3;
#pragma unroll
    for (int i = 0; i < 4; ++i) {
        float ps = 0.f, pd = 0.f;
#pragma unroll
        for (int j = 0; j < 8; ++j) {
            ps += acc[i][j] * al[head * 64 + j0 + j];
            pd += acc[i][j] * al[head * 64 + 32 + j0 + j];
        }
        ps += __shfl_xor(ps, 1); ps += __shfl_xor(ps, 2);
        pd += __shfl_xor(pd, 1); pd += __shfl_xor(pd, 2);
        const int g = g0 + i;
        if (ok[i]) {
            uint4 pk;
            pk.x = packbf2(acc[i][0], acc[i][1]);
            pk.y = packbf2(acc[i][2], acc[i][3]);
            pk.z = packbf2(acc[i][4], acc[i][5]);
            pk.w = packbf2(acc[i][6], acc[i][7]);
            *(uint4*)&hq[(size_t)g * 64 + (cbi << 2)] = pk;
            if ((cbi & 3) == 0) {
                usrc[g * NH + head] = make_float2(__expf(-ps), __expf(-SLOPE * ps));
                vdst[g * NH + head] = make_float2(__expf(-pd), __expf(-SLOPE * pd));
            }
        }
    }
}

// ---------------------------------------------------------------------------
// Scatter edges (packed srcl|dst) into fixed-capacity bucket regions.
// Edges cached in registers (16/thread, static-indexed): esrc/edst read ONCE,
// histogram and scatter passes both run from registers. Block reserves a run
// per nonempty bucket via atomicAdd(gcur) (gcur pre-set to b*BCAP by feat).
// Final gcur[b] - b*BCAP == bucket count (consumed by binfine).
// ---------------------------------------------------------------------------
__global__ __launch_bounds__(256) void binscatter_kernel(
    const int* __restrict__ esrc, const int* __restrict__ edst,
    int* __restrict__ gcur, unsigned int* __restrict__ binned,
    int n_edges, int nb)
{
    __shared__ int bc[MAXB];
    const int t = threadIdx.x;
    for (int i = t; i < nb; i += 256) bc[i] = 0;
    __syncthreads();

    const int base = blockIdx.x * EPB;
    const int end = min(base + EPB, n_edges);
    const bool full = (end - base) == EPB;

    int se[16], de[16];
    if (full) {
        const int4* s4p = (const int4*)(esrc + base);
        const int4* d4p = (const int4*)(edst + base);
#pragma unroll
        for (int j = 0; j < 4; ++j) {
            int4 s4 = s4p[j * 256 + t];
            int4 d4 = d4p[j * 256 + t];
            se[j * 4 + 0] = s4.x; se[j * 4 + 1] = s4.y;
            se[j * 4 + 2] = s4.z; se[j * 4 + 3] = s4.w;
            de[j * 4 + 0] = d4.x; de[j * 4 + 1] = d4.y;
            de[j * 4 + 2] = d4.z; de[j * 4 + 3] = d4.w;
        }
#pragma unroll
        for (int j = 0; j < 16; ++j)
            atomicAdd(&bc[se[j] >> BSH], 1);
    } else {
#pragma unroll
        for (int j = 0; j < 16; ++j) {
            const int e = base + j * 256 + t;
            se[j] = (e < end) ? esrc[e] : 0;
            de[j] = (e < end) ? edst[e] : 0;
            if (e < end) atomicAdd(&bc[se[j] >> BSH], 1);
        }
    }
    __syncthreads();

    // reserve a run per non-empty bucket; bc becomes the running cursor
    for (int i = t; i < nb; i += 256) {
        int c = bc[i];
        bc[i] = (c > 0) ? atomicAdd(&gcur[i], c) : 0;
    }
    __syncthreads();

    if (full) {
#pragma unroll
        for (int j = 0; j < 16; ++j) {
            int s = se[j];
            int pos = atomicAdd(&bc[s >> BSH], 1);
            binned[pos] = ((unsigned int)(s & (BNODES - 1)) << 17) | (unsigned int)de[j];
        }
    } else {
#pragma unroll
        for (int j = 0; j < 16; ++j) {
            const int e = base + j * 256 + t;
            if (e < end) {
                int s = se[j];
                int pos = atomicAdd(&bc[s >> BSH], 1);
                binned[pos] = ((unsigned int)(s & (BNODES - 1)) << 17) | (unsigned int)de[j];
            }
        }
    }
}

// ---------------------------------------------------------------------------
// Per-bucket fine sort, v3: stage the bucket's entries into LDS, per-node
// hist + scan, then scatter IN PLACE over the same global region (reads come
// from LDS, so no race; slots aliases binned). Writes offs/deg per node.
// ---------------------------------------------------------------------------
__global__ __launch_bounds__(256) void binfine_kernel(
    const int* __restrict__ gcur,
    int* __restrict__ offs, int* __restrict__ deg,
    unsigned int* __restrict__ binned,   // also the slots output (in place)
    int n_nodes)
{
    __shared__ unsigned int ebuf[BCAP];
    __shared__ int dcnt[BNODES];
    __shared__ int sc[BNODES];
    __shared__ int dcur[BNODES];
    const int t = threadIdx.x;
    const int b = blockIdx.x;
    const int base = b * BCAP;
    int cnt = gcur[b] - base;
    if (cnt > BCAP - 512) cnt = BCAP - 512;   // safety clamp (never triggers)
    const int node0 = b << BSH;

    for (int i = t; i < cnt; i += 256) ebuf[i] = binned[base + i];
    if (t < BNODES) dcnt[t] = 0;
    __syncthreads();

    for (int i = t; i < cnt; i += 256)
        atomicAdd(&dcnt[ebuf[i] >> 17], 1);
    __syncthreads();

    int pd = 0;
    if (t < BNODES) { pd = (dcnt[t] + 3) & ~3; sc[t] = pd; }
    __syncthreads();
    for (int off = 1; off < BNODES; off <<= 1) {
        int v = 0;
        if (t < BNODES && t >= off) v = sc[t - off];
        __syncthreads();
        if (t < BNODES) sc[t] += v;
        __syncthreads();
    }
    if (t < BNODES) {
        int o = base + sc[t] - pd;   // 4-aligned per-node start
        dcur[t] = o;
        int node = node0 + t;
        if (node < n_nodes) { offs[node] = o; deg[node] = dcnt[t]; }
    }
    __syncthreads();

    for (int i = t; i < cnt; i += 256) {
        unsigned int w = ebuf[i];
        int pos = atomicAdd(&dcur[w >> 17], 1);
        binned[pos] = w & 0x1ffffu;
    }
}

// ---------------------------------------------------------------------------
// Gather: 64 lanes per node, 2 cols per lane (bf16x2 h loads).
// 32-bit byte-offset addressing + 2-stage software pipeline.
// (Unchanged: sits on the scattered-256B-row L2-miss-path ceiling,
//  ~164 us / FETCH 500 MB stable across 5 rounds.)
// ---------------------------------------------------------------------------
__global__ __launch_bounds__(256) void gather_kernel(
    const int* __restrict__ slots, const int* __restrict__ offsets,
    const int* __restrict__ deg,
    const unsigned int* __restrict__ hv,    // [N*64] packed bf16 pairs
    const float2* __restrict__ usrc, const float2* __restrict__ vdst,
    float* __restrict__ out, int n_nodes)
{
    const int t = threadIdx.x;
    const int node = blockIdx.x * 4 + (t >> 6);
    if (node >= n_nodes) return;
    const int l = t & 63;          // cols {2l, 2l+1}
    const int head = l >> 4;
    const unsigned loff = (unsigned)l << 2;     // byte offset within hv row (256B)
    const unsigned hoff = (unsigned)head << 3;  // byte offset within vdst row (32B)
    const char* __restrict__ hvb = (const char*)hv;
    const char* __restrict__ vdb = (const char*)vdst;
    const float2 u = usrc[(unsigned)node * 4u + head];
    const int beg = offsets[node]; // multiple of 4
    const int d = deg[node];

    float ax0 = 0.f, ay0 = 0.f, ax1 = 0.f, ay1 = 0.f;
    float ax2 = 0.f, ay2 = 0.f, ax3 = 0.f, ay3 = 0.f;

#define LDV(c) (*(const float2*)(vdb + ((((unsigned)(c)) << 5) + hoff)))
#define LDW(c) (*(const unsigned int*)(hvb + ((((unsigned)(c)) << 8) + loff)))
#define COMP(vv, ww, AX, AY) do {                                   \
        float e_ = fminf(u.x * (vv).x, u.y * (vv).y);               \
        AX = fmaf(e_, __uint_as_float((ww) << 16), AX);             \
        AY = fmaf(e_, __uint_as_float((ww) & 0xffff0000u), AY);     \
    } while (0)

    int k = 0;
    if (d >= 4) {
        int4 cA = *(const int4*)(slots + beg);
        float2 vA0 = LDV(cA.x), vA1 = LDV(cA.y), vA2 = LDV(cA.z), vA3 = LDV(cA.w);
        unsigned wA0 = LDW(cA.x), wA1 = LDW(cA.y), wA2 = LDW(cA.z), wA3 = LDW(cA.w);

        for (; k + 12 <= d; k += 8) {
            int4 cB = *(const int4*)(slots + beg + k + 4);
            float2 vB0 = LDV(cB.x), vB1 = LDV(cB.y), vB2 = LDV(cB.z), vB3 = LDV(cB.w);
            unsigned wB0 = LDW(cB.x), wB1 = LDW(cB.y), wB2 = LDW(cB.z), wB3 = LDW(cB.w);
            COMP(vA0, wA0, ax0, ay0); COMP(vA1, wA1, ax1, ay1);
            COMP(vA2, wA2, ax2, ay2); COMP(vA3, wA3, ax3, ay3);
            int4 cN = *(const int4*)(slots + beg + k + 8);
            vA0 = LDV(cN.x); vA1 = LDV(cN.y); vA2 = LDV(cN.z); vA3 = LDV(cN.w);
            wA0 = LDW(cN.x); wA1 = LDW(cN.y); wA2 = LDW(cN.z); wA3 = LDW(cN.w);
            COMP(vB0, wB0, ax0, ay0); COMP(vB1, wB1, ax1, ay1);
            COMP(vB2, wB2, ax2, ay2); COMP(vB3, wB3, ax3, ay3);
        }
        if (k + 8 <= d) {
            int4 cB = *(const int4*)(slots + beg + k + 4);
            float2 vB0 = LDV(cB.x), vB1 = LDV(cB.y), vB2 = LDV(cB.z), vB3 = LDV(cB.w);
            unsigned wB0 = LDW(cB.x), wB1 = LDW(cB.y), wB2 = LDW(cB.z), wB3 = LDW(cB.w);
            COMP(vA0, wA0, ax0, ay0); COMP(vA1, wA1, ax1, ay1);
            COMP(vA2, wA2, ax2, ay2); COMP(vA3, wA3, ax3, ay3);
            COMP(vB0, wB0, ax0, ay0); COMP(vB1, wB1, ax1, ay1);
            COMP(vB2, wB2, ax2, ay2); COMP(vB3, wB3, ax3, ay3);
            k += 8;
        } else {
            COMP(vA0, wA0, ax0, ay0); COMP(vA1, wA1, ax1, ay1);
            COMP(vA2, wA2, ax2, ay2); COMP(vA3, wA3, ax3, ay3);
            k += 4;
        }
    }
    for (; k < d; ++k) {
        int c = slots[beg + k];
        float2 v = LDV(c);
        unsigned w = LDW(c);
        COMP(v, w, ax0, ay0);
    }
#undef LDV
#undef LDW
#undef COMP

    float rx = (ax0 + ax1) + (ax2 + ax3);
    float ry = (ay0 + ay1) + (ay2 + ay3);
    rx = rx > 0.f ? rx : __expf(rx) - 1.f;
    ry = ry > 0.f ? ry : __expf(ry) - 1.f;
    ((float2*)out)[(unsigned)node * 64u + l] = make_float2(rx, ry);
}

extern "C" void kernel_launch(void* const* d_in, const int* in_sizes, int n_in,
                              void* d_out, int out_size, void* d_ws, size_t ws_size,
                              hipStream_t stream)
{
    const float* x  = (const float*)d_in[0];
    const float* W  = (const float*)d_in[1];
    const float* a  = (const float*)d_in[2];
    const int* esrc = (const int*)d_in[3];
    const int* edst = (const int*)d_in[4];
    const int n_nodes = in_sizes[0] / DIN;
    const int n_edges = in_sizes[3];
    float* out = (float*)d_out;

    const int nb = (n_nodes + BNODES - 1) >> BSH;

    // workspace layout (~47 MB)
    unsigned int* hq = (unsigned int*)d_ws;                 // [N*64] bf16 pairs, 25.6MB
    float2* usrc = (float2*)(hq + (size_t)n_nodes * 64);    // [N*4]
    float2* vdst = usrc + (size_t)n_nodes * NH;             // [N*4]
    int* offs   = (int*)(vdst + (size_t)n_nodes * NH);      // [N]
    int* deg    = offs + n_nodes;                           // [N]
    int* gcur   = deg + n_nodes;                            // [MAXB]
    unsigned int* binned = (unsigned int*)(gcur + MAXB);    // [nb*BCAP] = slots (in place)

    feat_kernel<<<(n_nodes + NPBF - 1) / NPBF, 256, 0, stream>>>(
        x, W, a, hq, usrc, vdst, gcur, n_nodes, nb);

    binscatter_kernel<<<(n_edges + EPB - 1) / EPB, 256, 0, stream>>>(
        esrc, edst, gcur, binned, n_edges, nb);

    binfine_kernel<<<nb, 256, 0, stream>>>(
        gcur, offs, deg, binned, n_nodes);

    gather_kernel<<<(n_nodes + 3) / 4, 256, 0, stream>>>(
        (const int*)binned, offs, deg, hq, usrc, vdst, out, n_nodes);
}

// Round 6
// 418.669 us; speedup vs baseline: 2.3683x; 1.0111x over previous
//
#include <hip/hip_runtime.h>
#include <hip/hip_bf16.h>

#define DIN 96
#define DOUT 32
#define NH 4
#define DTOT 128          // NH * DOUT, concat output width
#define SLOPE 0.2f
#define NPBF 64           // nodes per block in feat role (4 per thread)
#define BSH 7             // bucket shift: 128 src nodes per bucket
#define BNODES 128
#define MAXB 1024         // max buckets (N <= 131072)
#define EPB 4096          // edges per scatter-role block
#define BCAP 5632         // fixed bucket capacity: E/nb=4096 avg +24 sigma,
                          // >= clamped cnt (5120) + 3*128 pad for 4-aligned slots

// pack two fp32 -> two bf16 (RNE) in one uint
__device__ __forceinline__ unsigned int packbf2(float lo, float hi) {
    unsigned int a = __float_as_uint(lo), b = __float_as_uint(hi);
    a += 0x7fffu + ((a >> 16) & 1u);
    b += 0x7fffu + ((b >> 16) & 1u);
    return (a >> 16) | (b & 0xffff0000u);
}

// ---------------------------------------------------------------------------
// prep_kernel: fused  [scatter role]  ||  [feat role]
// Role split by blockIdx%3 (1 scatter : 2 feat) so every CU overlaps the
// memory/atomic-bound scatter with the VALU-bound feat. Roles are data-
// independent. Scatter aliases its LDS hist over the feat W tile.
//
// scatter role: stage 16 edges/thread in registers (esrc/edst read ONCE),
//   LDS bucket hist, reserve run via atomicAdd(gcur0[b]) (zero-based; region
//   base b*BCAP added here), scatter packed (srcl|dst) words into binned.
//   Final gcur0[b] == bucket count.
// feat role: h[n] = x[n] @ W (all heads) -> packed bf16 hq, plus per-node
//   attention exp factors usrc/vdst. 4 nodes/thread, Wlo/Whi split planes,
//   float4 x loads. 49.25KB LDS -> 3 blocks/CU.
// ---------------------------------------------------------------------------
__global__ __launch_bounds__(256) void prep_kernel(
    const float* __restrict__ x, const float* __restrict__ W,
    const float* __restrict__ a,
    const int* __restrict__ esrc, const int* __restrict__ edst,
    unsigned int* __restrict__ hq,      // [N*64] packed bf16 pairs
    float2* __restrict__ usrc, float2* __restrict__ vdst,
    int* __restrict__ gcur0, unsigned int* __restrict__ binned,
    int n_nodes, int n_edges, int nb, int sblocks, int fblocks)
{
    __shared__ float Wlo[DIN * 64];     // feat: [k][cbi*4+jj]; scatter: bc alias
    __shared__ float Whi[DIN * 64];
    __shared__ float al[NH * 2 * DOUT];
    const int t = threadIdx.x;
    const int bid = (int)blockIdx.x;
    const int q3 = bid / 3;
    const int r3 = bid - q3 * 3;

    if (r3 == 0 && q3 < sblocks) {
        // ------------------------- scatter role -------------------------
        int* bc = (int*)Wlo;            // 4KB alias, never used by this role's W
        for (int i = t; i < nb; i += 256) bc[i] = 0;
        __syncthreads();

        const int base = q3 * EPB;
        const int end = min(base + EPB, n_edges);
        const bool full = (end - base) == EPB;

        int se[16], de[16];
        if (full) {
            const int4* s4p = (const int4*)(esrc + base);
            const int4* d4p = (const int4*)(edst + base);
#pragma unroll
            for (int j = 0; j < 4; ++j) {
                int4 s4 = s4p[j * 256 + t];
                int4 d4 = d4p[j * 256 + t];
                se[j * 4 + 0] = s4.x; se[j * 4 + 1] = s4.y;
                se[j * 4 + 2] = s4.z; se[j * 4 + 3] = s4.w;
                de[j * 4 + 0] = d4.x; de[j * 4 + 1] = d4.y;
                de[j * 4 + 2] = d4.z; de[j * 4 + 3] = d4.w;
            }
#pragma unroll
            for (int j = 0; j < 16; ++j)
                atomicAdd(&bc[se[j] >> BSH], 1);
        } else {
#pragma unroll
            for (int j = 0; j < 16; ++j) {
                const int e = base + j * 256 + t;
                se[j] = (e < end) ? esrc[e] : 0;
                de[j] = (e < end) ? edst[e] : 0;
                if (e < end) atomicAdd(&bc[se[j] >> BSH], 1);
            }
        }
        __syncthreads();

        // reserve a run per non-empty bucket; bc becomes the global cursor
        for (int i = t; i < nb; i += 256) {
            int c = bc[i];
            bc[i] = (c > 0) ? (i * BCAP + atomicAdd(&gcur0[i], c)) : 0;
        }
        __syncthreads();

        if (full) {
#pragma unroll
            for (int j = 0; j < 16; ++j) {
                int s = se[j];
                int pos = atomicAdd(&bc[s >> BSH], 1);
                binned[pos] = ((unsigned int)(s & (BNODES - 1)) << 17) | (unsigned int)de[j];
            }
        } else {
#pragma unroll
            for (int j = 0; j < 16; ++j) {
                const int e = base + j * 256 + t;
                if (e < end) {
                    int s = se[j];
                    int pos = atomicAdd(&bc[s >> BSH], 1);
                    binned[pos] = ((unsigned int)(s & (BNODES - 1)) << 17) | (unsigned int)de[j];
                }
            }
        }
        return;
    }

    // --------------------------- feat role ---------------------------
    const int fid = bid - min(q3 + (r3 ? 1 : 0), sblocks);
    if (fid >= fblocks) return;

    // stage W: linear read (coalesced), split write into lo/hi planes
    for (int i = t; i < DIN * DTOT; i += 256) {
        int k = i >> 7, c = i & 127;        // c = output col 0..127
        int head = c >> 5, j = c & 31;
        float w = W[head * (DIN * DOUT) + k * DOUT + j];
        int cbi = c >> 3, jj = c & 7;
        if (jj < 4) Wlo[(k << 6) + (cbi << 2) + jj] = w;
        else        Whi[(k << 6) + (cbi << 2) + (jj - 4)] = w;
    }
    for (int i = t; i < NH * 2 * DOUT; i += 256) al[i] = a[i];
    __syncthreads();

    const int cbi = t & 15;             // column block: cols 8*cbi .. 8*cbi+7
    const int ng = t >> 4;              // node group (4 nodes)
    const int node0 = fid * NPBF;
    const int g0 = node0 + ng * 4;

    bool ok[4];
    const float* xp[4];
#pragma unroll
    for (int i = 0; i < 4; ++i) {
        ok[i] = (g0 + i) < n_nodes;
        xp[i] = x + (size_t)(g0 + i) * DIN;
    }

    float acc[4][8];
#pragma unroll
    for (int i = 0; i < 4; ++i)
#pragma unroll
        for (int j = 0; j < 8; ++j) acc[i][j] = 0.f;

    for (int k = 0; k < DIN; k += 4) {
        float4 xv[4];
#pragma unroll
        for (int i = 0; i < 4; ++i)
            xv[i] = ok[i] ? *(const float4*)(xp[i] + k)
                          : make_float4(0.f, 0.f, 0.f, 0.f);
#pragma unroll
        for (int kk = 0; kk < 4; ++kk) {
            const float4 wlo = *(const float4*)&Wlo[((k + kk) << 6) + (cbi << 2)];
            const float4 whi = *(const float4*)&Whi[((k + kk) << 6) + (cbi << 2)];
#pragma unroll
            for (int i = 0; i < 4; ++i) {
                const float xvv = (kk == 0) ? xv[i].x : (kk == 1) ? xv[i].y
                                 : (kk == 2) ? xv[i].z : xv[i].w;
                acc[i][0] = fmaf(xvv, wlo.x, acc[i][0]);
                acc[i][1] = fmaf(xvv, wlo.y, acc[i][1]);
                acc[i][2] = fmaf(xvv, wlo.z, acc[i][2]);
                acc[i][3] = fmaf(xvv, wlo.w, acc[i][3]);
                acc[i][4] = fmaf(xvv, whi.x, acc[i][4]);
                acc[i][5] = fmaf(xvv, whi.y, acc[i][5]);
                acc[i][6] = fmaf(xvv, whi.z, acc[i][6]);
                acc[i][7] = fmaf(xvv, whi.w, acc[i][7]);
            }
        }
    }

    const int head = cbi >> 2;
    const int j0 = (cbi & 3) << 3;
#pragma unroll
    for (int i = 0; i < 4; ++i) {
        float ps = 0.f, pd = 0.f;
#pragma unroll
        for (int j = 0; j < 8; ++j) {
            ps += acc[i][j] * al[head * 64 + j0 + j];
            pd += acc[i][j] * al[head * 64 + 32 + j0 + j];
        }
        ps += __shfl_xor(ps, 1); ps += __shfl_xor(ps, 2);
        pd += __shfl_xor(pd, 1); pd += __shfl_xor(pd, 2);
        const int g = g0 + i;
        if (ok[i]) {
            uint4 pk;
            pk.x = packbf2(acc[i][0], acc[i][1]);
            pk.y = packbf2(acc[i][2], acc[i][3]);
            pk.z = packbf2(acc[i][4], acc[i][5]);
            pk.w = packbf2(acc[i][6], acc[i][7]);
            *(uint4*)&hq[(size_t)g * 64 + (cbi << 2)] = pk;
            if ((cbi & 3) == 0) {
                usrc[g * NH + head] = make_float2(__expf(-ps), __expf(-SLOPE * ps));
                vdst[g * NH + head] = make_float2(__expf(-pd), __expf(-SLOPE * pd));
            }
        }
    }
}

// ---------------------------------------------------------------------------
// bucket_kernel: fused fine-sort + gather, one block per bucket, 512 threads.
// Sort phase: hist binned (global, coalesced), scan 128 padded degrees,
// scatter sorted dst indices into LDS slist (no global slots/offs/deg).
// Gather phase: 8 waves x 16 rounds = 128 nodes; 64 lanes per node, 2 cols
// per lane; slot reads are LDS broadcasts; hv/vdst loads use the proven
// 32-bit byte-offset + 2-stage pipeline. 23.5KB LDS -> all 782 blocks
// co-resident at ~24 waves/CU (matches the standalone gather's occupancy).
// ---------------------------------------------------------------------------
__global__ __launch_bounds__(512) void bucket_kernel(
    const int* __restrict__ gcur0,
    const unsigned int* __restrict__ binned,
    const unsigned int* __restrict__ hv,    // [N*64] packed bf16 pairs
    const float2* __restrict__ usrc, const float2* __restrict__ vdst,
    float* __restrict__ out, int n_nodes)
{
    __shared__ int slist[BCAP];
    __shared__ int dcnt[BNODES];
    __shared__ int sc[BNODES];
    __shared__ int dcur[BNODES];
    const int t = threadIdx.x;
    const int b = (int)blockIdx.x;
    const unsigned base = (unsigned)b * BCAP;
    int cnt = gcur0[b];
    if (cnt > BCAP - 512) cnt = BCAP - 512;   // safety clamp (never triggers)
    const int node0 = b << BSH;

    if (t < BNODES) dcnt[t] = 0;
    __syncthreads();
    for (int i = t; i < cnt; i += 512)
        atomicAdd(&dcnt[binned[base + i] >> 17], 1);
    __syncthreads();
    int pd = 0;
    if (t < BNODES) { pd = (dcnt[t] + 3) & ~3; sc[t] = pd; }
    __syncthreads();
    for (int off = 1; off < BNODES; off <<= 1) {
        int v = 0;
        if (t < BNODES && t >= off) v = sc[t - off];
        __syncthreads();
        if (t < BNODES) sc[t] += v;
        __syncthreads();
    }
    if (t < BNODES) dcur[t] = sc[t] - pd;     // local 4-aligned start
    __syncthreads();
    for (int i = t; i < cnt; i += 512) {
        unsigned int w = binned[base + i];
        int pos = atomicAdd(&dcur[w >> 17], 1);
        slist[pos] = (int)(w & 0x1ffffu);
    }
    __syncthreads();
    // dcur[n] is now start+deg, so start = dcur[n] - dcnt[n]

    // ------------------------- gather phase -------------------------
    const int l = t & 63;          // cols {2l, 2l+1}
    const int head = l >> 4;
    const unsigned loff = (unsigned)l << 2;     // byte offset in hv row (256B)
    const unsigned hoff = (unsigned)head << 3;  // byte offset in vdst row (32B)
    const char* __restrict__ hvb = (const char*)hv;
    const char* __restrict__ vdb = (const char*)vdst;
    const int sub = t >> 6;        // wave id 0..7 (uniform per wave)

#define LDV(c) (*(const float2*)(vdb + ((((unsigned)(c)) << 5) + hoff)))
#define LDW(c) (*(const unsigned int*)(hvb + ((((unsigned)(c)) << 8) + loff)))
#define COMP(vv, ww, AX, AY) do {                                   \
        float e_ = fminf(u.x * (vv).x, u.y * (vv).y);               \
        AX = fmaf(e_, __uint_as_float((ww) << 16), AX);             \
        AY = fmaf(e_, __uint_as_float((ww) & 0xffff0000u), AY);     \
    } while (0)

    for (int q = 0; q < BNODES / 8; ++q) {
        const int nd = q * 8 + sub;
        const int node = node0 + nd;
        if (node >= n_nodes) break;           // wave-uniform exit
        const int d = dcnt[nd];
        const int beg = dcur[nd] - d;         // local, multiple of 4
        const float2 u = usrc[(unsigned)node * 4u + head];

        float ax0 = 0.f, ay0 = 0.f, ax1 = 0.f, ay1 = 0.f;
        float ax2 = 0.f, ay2 = 0.f, ax3 = 0.f, ay3 = 0.f;
        int k = 0;
        if (d >= 4) {
            int4 cA = *(const int4*)&slist[beg];
            float2 vA0 = LDV(cA.x), vA1 = LDV(cA.y), vA2 = LDV(cA.z), vA3 = LDV(cA.w);
            unsigned wA0 = LDW(cA.x), wA1 = LDW(cA.y), wA2 = LDW(cA.z), wA3 = LDW(cA.w);

            for (; k + 12 <= d; k += 8) {
                int4 cB = *(const int4*)&slist[beg + k + 4];
                float2 vB0 = LDV(cB.x), vB1 = LDV(cB.y), vB2 = LDV(cB.z), vB3 = LDV(cB.w);
                unsigned wB0 = LDW(cB.x), wB1 = LDW(cB.y), wB2 = LDW(cB.z), wB3 = LDW(cB.w);
                COMP(vA0, wA0, ax0, ay0); COMP(vA1, wA1, ax1, ay1);
                COMP(vA2, wA2, ax2, ay2); COMP(vA3, wA3, ax3, ay3);
                int4 cN = *(const int4*)&slist[beg + k + 8];
                vA0 = LDV(cN.x); vA1 = LDV(cN.y); vA2 = LDV(cN.z); vA3 = LDV(cN.w);
                wA0 = LDW(cN.x); wA1 = LDW(cN.y); wA2 = LDW(cN.z); wA3 = LDW(cN.w);
                COMP(vB0, wB0, ax0, ay0); COMP(vB1, wB1, ax1, ay1);
                COMP(vB2, wB2, ax2, ay2); COMP(vB3, wB3, ax3, ay3);
            }
            if (k + 8 <= d) {
                int4 cB = *(const int4*)&slist[beg + k + 4];
                float2 vB0 = LDV(cB.x), vB1 = LDV(cB.y), vB2 = LDV(cB.z), vB3 = LDV(cB.w);
                unsigned wB0 = LDW(cB.x), wB1 = LDW(cB.y), wB2 = LDW(cB.z), wB3 = LDW(cB.w);
                COMP(vA0, wA0, ax0, ay0); COMP(vA1, wA1, ax1, ay1);
                COMP(vA2, wA2, ax2, ay2); COMP(vA3, wA3, ax3, ay3);
                COMP(vB0, wB0, ax0, ay0); COMP(vB1, wB1, ax1, ay1);
                COMP(vB2, wB2, ax2, ay2); COMP(vB3, wB3, ax3, ay3);
                k += 8;
            } else {
                COMP(vA0, wA0, ax0, ay0); COMP(vA1, wA1, ax1, ay1);
                COMP(vA2, wA2, ax2, ay2); COMP(vA3, wA3, ax3, ay3);
                k += 4;
            }
        }
        for (; k < d; ++k) {
            int c = slist[beg + k];
            float2 v = LDV(c);
            unsigned w = LDW(c);
            COMP(v, w, ax0, ay0);
        }
        float rx = (ax0 + ax1) + (ax2 + ax3);
        float ry = (ay0 + ay1) + (ay2 + ay3);
        rx = rx > 0.f ? rx : __expf(rx) - 1.f;
        ry = ry > 0.f ? ry : __expf(ry) - 1.f;
        ((float2*)out)[(unsigned)node * 64u + l] = make_float2(rx, ry);
    }
#undef LDV
#undef LDW
#undef COMP
}

extern "C" void kernel_launch(void* const* d_in, const int* in_sizes, int n_in,
                              void* d_out, int out_size, void* d_ws, size_t ws_size,
                              hipStream_t stream)
{
    const float* x  = (const float*)d_in[0];
    const float* W  = (const float*)d_in[1];
    const float* a  = (const float*)d_in[2];
    const int* esrc = (const int*)d_in[3];
    const int* edst = (const int*)d_in[4];
    const int n_nodes = in_sizes[0] / DIN;
    const int n_edges = in_sizes[3];
    float* out = (float*)d_out;

    const int nb = (n_nodes + BNODES - 1) >> BSH;

    // workspace layout (~46.5 MB)
    unsigned int* hq = (unsigned int*)d_ws;                 // [N*64] bf16 pairs, 25.6MB
    float2* usrc = (float2*)(hq + (size_t)n_nodes * 64);    // [N*4]
    float2* vdst = usrc + (size_t)n_nodes * NH;             // [N*4]
    int* gcur0  = (int*)(vdst + (size_t)n_nodes * NH);      // [MAXB]
    unsigned int* binned = (unsigned int*)(gcur0 + MAXB);   // [nb*BCAP], 17.6MB

    hipMemsetAsync(gcur0, 0, MAXB * sizeof(int), stream);

    const int SB = (n_edges + EPB - 1) / EPB;
    const int FB = (n_nodes + NPBF - 1) / NPBF;
    int grid = SB + FB;
    if (grid < 3 * SB - 2) grid = 3 * SB - 2;

    prep_kernel<<<grid, 256, 0, stream>>>(
        x, W, a, esrc, edst, hq, usrc, vdst, gcur0, binned,
        n_nodes, n_edges, nb, SB, FB);

    bucket_kernel<<<nb, 512, 0, stream>>>(
        gcur0, binned, hq, usrc, vdst, out, n_nodes);
}

// Round 7
// 413.103 us; speedup vs baseline: 2.4002x; 1.0135x over previous
//
#include <hip/hip_runtime.h>
#include <hip/hip_bf16.h>

#define DIN 96
#define DOUT 32
#define NH 4
#define DTOT 128          // NH * DOUT, concat output width
#define SLOPE 0.2f
#define NPBF 64           // nodes per block in feat_kernel (4 per thread)
#define BSH 7             // bucket shift: 128 src nodes per parent bucket
#define BNODES 128
#define MAXB 1024         // max parent buckets (N <= 131072)
#define EPB 4096          // edges per scatter block
#define BCAP 5632         // fixed parent-bucket capacity (E/nb=4096 avg +24 sigma)
#define QSL  2304         // quarter wbuf capacity (avg 1024, +39 sigma)
#define SLSZ 2432         // quarter slist capacity (QSL + 32*4 pad slack)

// pack two fp32 -> two bf16 (RNE) in one uint
__device__ __forceinline__ unsigned int packbf2(float lo, float hi) {
    unsigned int a = __float_as_uint(lo), b = __float_as_uint(hi);
    a += 0x7fffu + ((a >> 16) & 1u);
    b += 0x7fffu + ((b >> 16) & 1u);
    return (a >> 16) | (b & 0xffff0000u);
}

// ---------------------------------------------------------------------------
// feat_kernel (proven R2 form): h[n] = x[n] @ W (all heads) -> packed bf16,
// plus per-node attention exp factors.
//   - 4 nodes/thread (64 nodes/block): 32 FMA per W-fragment read
//   - W split into Wlo/Whi planes -> ds_read_b128 at 16B stride, bank-clean
//   - 49.25 KB LDS -> 3 blocks/CU
// ---------------------------------------------------------------------------
__global__ __launch_bounds__(256) void feat_kernel(
    const float* __restrict__ x, const float* __restrict__ W,
    const float* __restrict__ a,
    unsigned int* __restrict__ hq,      // [N*64] packed bf16 pairs
    float2* __restrict__ usrc, float2* __restrict__ vdst,
    int n_nodes)
{
    __shared__ float Wlo[DIN * 64];     // [k][cbi*4 + jj], cols 8*cbi + jj
    __shared__ float Whi[DIN * 64];     // [k][cbi*4 + jj], cols 8*cbi + 4 + jj
    __shared__ float al[NH * 2 * DOUT];
    const int t = threadIdx.x;

    for (int i = t; i < DIN * DTOT; i += 256) {
        int k = i >> 7, c = i & 127;        // c = output col 0..127
        int head = c >> 5, j = c & 31;
        float w = W[head * (DIN * DOUT) + k * DOUT + j];
        int cbi = c >> 3, jj = c & 7;
        if (jj < 4) Wlo[(k << 6) + (cbi << 2) + jj] = w;
        else        Whi[(k << 6) + (cbi << 2) + (jj - 4)] = w;
    }
    for (int i = t; i < NH * 2 * DOUT; i += 256) al[i] = a[i];
    __syncthreads();

    const int cbi = t & 15;             // column block: cols 8*cbi .. 8*cbi+7
    const int ng = t >> 4;              // node group (4 nodes)
    const int node0 = blockIdx.x * NPBF;
    const int g0 = node0 + ng * 4;

    bool ok[4];
    const float* xp[4];
#pragma unroll
    for (int i = 0; i < 4; ++i) {
        ok[i] = (g0 + i) < n_nodes;
        xp[i] = x + (size_t)(g0 + i) * DIN;
    }

    float acc[4][8];
#pragma unroll
    for (int i = 0; i < 4; ++i)
#pragma unroll
        for (int j = 0; j < 8; ++j) acc[i][j] = 0.f;

    for (int k = 0; k < DIN; k += 4) {
        float4 xv[4];
#pragma unroll
        for (int i = 0; i < 4; ++i)
            xv[i] = ok[i] ? *(const float4*)(xp[i] + k)
                          : make_float4(0.f, 0.f, 0.f, 0.f);
#pragma unroll
        for (int kk = 0; kk < 4; ++kk) {
            const float4 wlo = *(const float4*)&Wlo[((k + kk) << 6) + (cbi << 2)];
            const float4 whi = *(const float4*)&Whi[((k + kk) << 6) + (cbi << 2)];
#pragma unroll
            for (int i = 0; i < 4; ++i) {
                const float xvv = (kk == 0) ? xv[i].x : (kk == 1) ? xv[i].y
                                 : (kk == 2) ? xv[i].z : xv[i].w;
                acc[i][0] = fmaf(xvv, wlo.x, acc[i][0]);
                acc[i][1] = fmaf(xvv, wlo.y, acc[i][1]);
                acc[i][2] = fmaf(xvv, wlo.z, acc[i][2]);
                acc[i][3] = fmaf(xvv, wlo.w, acc[i][3]);
                acc[i][4] = fmaf(xvv, whi.x, acc[i][4]);
                acc[i][5] = fmaf(xvv, whi.y, acc[i][5]);
                acc[i][6] = fmaf(xvv, whi.z, acc[i][6]);
                acc[i][7] = fmaf(xvv, whi.w, acc[i][7]);
            }
        }
    }

    const int head = cbi >> 2;
    const int j0 = (cbi & 3) << 3;
#pragma unroll
    for (int i = 0; i < 4; ++i) {
        float ps = 0.f, pd = 0.f;
#pragma unroll
        for (int j = 0; j < 8; ++j) {
            ps += acc[i][j] * al[head * 64 + j0 + j];
            pd += acc[i][j] * al[head * 64 + 32 + j0 + j];
        }
        ps += __shfl_xor(ps, 1); ps += __shfl_xor(ps, 2);
        pd += __shfl_xor(pd, 1); pd += __shfl_xor(pd, 2);
        const int g = g0 + i;
        if (ok[i]) {
            uint4 pk;
            pk.x = packbf2(acc[i][0], acc[i][1]);
            pk.y = packbf2(acc[i][2], acc[i][3]);
            pk.z = packbf2(acc[i][4], acc[i][5]);
            pk.w = packbf2(acc[i][6], acc[i][7]);
            *(uint4*)&hq[(size_t)g * 64 + (cbi << 2)] = pk;
            if ((cbi & 3) == 0) {
                usrc[g * NH + head] = make_float2(__expf(-ps), __expf(-SLOPE * ps));
                vdst[g * NH + head] = make_float2(__expf(-pd), __expf(-SLOPE * pd));
            }
        }
    }
}

// ---------------------------------------------------------------------------
// binscatter (standalone, R6 role verbatim): scatter edges (packed srcl|dst)
// into fixed-capacity parent-bucket regions. 16 edges/thread reg-staged,
// LDS hist, run reservation via atomicAdd(gcur0) (zero-based; memset'd).
// Final gcur0[b] == bucket count.
// ---------------------------------------------------------------------------
__global__ __launch_bounds__(256) void binscatter_kernel(
    const int* __restrict__ esrc, const int* __restrict__ edst,
    int* __restrict__ gcur0, unsigned int* __restrict__ binned,
    int n_edges, int nb)
{
    __shared__ int bc[MAXB];
    const int t = threadIdx.x;
    for (int i = t; i < nb; i += 256) bc[i] = 0;
    __syncthreads();

    const int base = blockIdx.x * EPB;
    const int end = min(base + EPB, n_edges);
    const bool full = (end - base) == EPB;

    int se[16], de[16];
    if (full) {
        const int4* s4p = (const int4*)(esrc + base);
        const int4* d4p = (const int4*)(edst + base);
#pragma unroll
        for (int j = 0; j < 4; ++j) {
            int4 s4 = s4p[j * 256 + t];
            int4 d4 = d4p[j * 256 + t];
            se[j * 4 + 0] = s4.x; se[j * 4 + 1] = s4.y;
            se[j * 4 + 2] = s4.z; se[j * 4 + 3] = s4.w;
            de[j * 4 + 0] = d4.x; de[j * 4 + 1] = d4.y;
            de[j * 4 + 2] = d4.z; de[j * 4 + 3] = d4.w;
        }
#pragma unroll
        for (int j = 0; j < 16; ++j)
            atomicAdd(&bc[se[j] >> BSH], 1);
    } else {
#pragma unroll
        for (int j = 0; j < 16; ++j) {
            const int e = base + j * 256 + t;
            se[j] = (e < end) ? esrc[e] : 0;
            de[j] = (e < end) ? edst[e] : 0;
            if (e < end) atomicAdd(&bc[se[j] >> BSH], 1);
        }
    }
    __syncthreads();

    for (int i = t; i < nb; i += 256) {
        int c = bc[i];
        bc[i] = (c > 0) ? (i * BCAP + atomicAdd(&gcur0[i], c)) : 0;
    }
    __syncthreads();

    if (full) {
#pragma unroll
        for (int j = 0; j < 16; ++j) {
            int s = se[j];
            int pos = atomicAdd(&bc[s >> BSH], 1);
            binned[pos] = ((unsigned int)(s & (BNODES - 1)) << 17) | (unsigned int)de[j];
        }
    } else {
#pragma unroll
        for (int j = 0; j < 16; ++j) {
            const int e = base + j * 256 + t;
            if (e < end) {
                int s = se[j];
                int pos = atomicAdd(&bc[s >> BSH], 1);
                binned[pos] = ((unsigned int)(s & (BNODES - 1)) << 17) | (unsigned int)de[j];
            }
        }
    }
}

// ---------------------------------------------------------------------------
// bucket_kernel v2: 4 quarter-blocks per parent bucket (load balance fix).
// Block (p,q) owns the 32 nodes [p*128 + q*32, +32). One pass over the
// parent's binned words keeps quarter matches into compact LDS wbuf + hist;
// 32-entry scan; LDS fine-sort into slist; then the proven register-pipeline
// gather (8 waves x 4 rounds, full 128-col row per node -> hv traffic
// identical, node sets disjoint). ~19.3 KB LDS -> wave-capped 4 blocks/CU,
// 3128 blocks = ~3 scheduling rounds -> dynamic balancing (tail ~8% vs 31%).
// ---------------------------------------------------------------------------
__global__ __launch_bounds__(512) void bucket_kernel(
    const int* __restrict__ gcur0,
    const unsigned int* __restrict__ binned,
    const unsigned int* __restrict__ hv,    // [N*64] packed bf16 pairs
    const float2* __restrict__ usrc, const float2* __restrict__ vdst,
    float* __restrict__ out, int n_nodes)
{
    __shared__ unsigned int wbuf[QSL];
    __shared__ __align__(16) int slist[SLSZ];
    __shared__ int dcnt[32];
    __shared__ int sc[32];
    __shared__ int dcur[32];
    __shared__ int qn_s;
    const int t = threadIdx.x;
    const int p = (int)blockIdx.x >> 2;
    const int q = (int)blockIdx.x & 3;
    const unsigned pbase = (unsigned)p * BCAP;
    int cnt = gcur0[p];
    if (cnt > BCAP - 512) cnt = BCAP - 512;   // safety clamp (never triggers)
    const int node0 = (p << BSH) + (q << 5);

    if (t < 32) dcnt[t] = 0;
    if (t == 0) qn_s = 0;
    __syncthreads();

    // single filtered pass: compact quarter's words into wbuf + histogram
    for (int i = t; i < cnt; i += 512) {
        unsigned int w = binned[pbase + i];
        int s = (int)(w >> 17);
        if ((s >> 5) == q) {
            int pos = atomicAdd(&qn_s, 1);
            if (pos < QSL) {
                wbuf[pos] = w;
                atomicAdd(&dcnt[s & 31], 1);
            }
        }
    }
    __syncthreads();
    int qn = qn_s; if (qn > QSL) qn = QSL;

    int pd = 0;
    if (t < 32) { pd = (dcnt[t] + 3) & ~3; sc[t] = pd; }
    __syncthreads();
    for (int off = 1; off < 32; off <<= 1) {
        int v = 0;
        if (t < 32 && t >= off) v = sc[t - off];
        __syncthreads();
        if (t < 32) sc[t] += v;
        __syncthreads();
    }
    if (t < 32) dcur[t] = sc[t] - pd;     // local 4-aligned start
    __syncthreads();
    for (int i = t; i < qn; i += 512) {
        unsigned int w = wbuf[i];
        int pos = atomicAdd(&dcur[(w >> 17) & 31], 1);
        slist[pos] = (int)(w & 0x1ffffu);
    }
    __syncthreads();
    // dcur[n] is now start+deg, so start = dcur[n] - dcnt[n]

    // ------------------------- gather phase -------------------------
    const int l = t & 63;          // cols {2l, 2l+1}
    const int head = l >> 4;
    const unsigned loff = (unsigned)l << 2;     // byte offset in hv row (256B)
    const unsigned hoff = (unsigned)head << 3;  // byte offset in vdst row (32B)
    const char* __restrict__ hvb = (const char*)hv;
    const char* __restrict__ vdb = (const char*)vdst;
    const int sub = t >> 6;        // wave id 0..7 (uniform per wave)

#define LDV(c) (*(const float2*)(vdb + ((((unsigned)(c)) << 5) + hoff)))
#define LDW(c) (*(const unsigned int*)(hvb + ((((unsigned)(c)) << 8) + loff)))
#define COMP(vv, ww, AX, AY) do {                                   \
        float e_ = fminf(u.x * (vv).x, u.y * (vv).y);               \
        AX = fmaf(e_, __uint_as_float((ww) << 16), AX);             \
        AY = fmaf(e_, __uint_as_float((ww) & 0xffff0000u), AY);     \
    } while (0)

    for (int r = 0; r < 4; ++r) {
        const int nd = r * 8 + sub;
        const int node = node0 + nd;
        if (node >= n_nodes) break;           // wave-uniform exit
        const int d = dcnt[nd];
        const int beg = dcur[nd] - d;         // local, multiple of 4
        const float2 u = usrc[(unsigned)node * 4u + head];

        float ax0 = 0.f, ay0 = 0.f, ax1 = 0.f, ay1 = 0.f;
        float ax2 = 0.f, ay2 = 0.f, ax3 = 0.f, ay3 = 0.f;
        int k = 0;
        if (d >= 4) {
            int4 cA = *(const int4*)&slist[beg];
            float2 vA0 = LDV(cA.x), vA1 = LDV(cA.y), vA2 = LDV(cA.z), vA3 = LDV(cA.w);
            unsigned wA0 = LDW(cA.x), wA1 = LDW(cA.y), wA2 = LDW(cA.z), wA3 = LDW(cA.w);

            for (; k + 12 <= d; k += 8) {
                int4 cB = *(const int4*)&slist[beg + k + 4];
                float2 vB0 = LDV(cB.x), vB1 = LDV(cB.y), vB2 = LDV(cB.z), vB3 = LDV(cB.w);
                unsigned wB0 = LDW(cB.x), wB1 = LDW(cB.y), wB2 = LDW(cB.z), wB3 = LDW(cB.w);
                COMP(vA0, wA0, ax0, ay0); COMP(vA1, wA1, ax1, ay1);
                COMP(vA2, wA2, ax2, ay2); COMP(vA3, wA3, ax3, ay3);
                int4 cN = *(const int4*)&slist[beg + k + 8];
                vA0 = LDV(cN.x); vA1 = LDV(cN.y); vA2 = LDV(cN.z); vA3 = LDV(cN.w);
                wA0 = LDW(cN.x); wA1 = LDW(cN.y); wA2 = LDW(cN.z); wA3 = LDW(cN.w);
                COMP(vB0, wB0, ax0, ay0); COMP(vB1, wB1, ax1, ay1);
                COMP(vB2, wB2, ax2, ay2); COMP(vB3, wB3, ax3, ay3);
            }
            if (k + 8 <= d) {
                int4 cB = *(const int4*)&slist[beg + k + 4];
                float2 vB0 = LDV(cB.x), vB1 = LDV(cB.y), vB2 = LDV(cB.z), vB3 = LDV(cB.w);
                unsigned wB0 = LDW(cB.x), wB1 = LDW(cB.y), wB2 = LDW(cB.z), wB3 = LDW(cB.w);
                COMP(vA0, wA0, ax0, ay0); COMP(vA1, wA1, ax1, ay1);
                COMP(vA2, wA2, ax2, ay2); COMP(vA3, wA3, ax3, ay3);
                COMP(vB0, wB0, ax0, ay0); COMP(vB1, wB1, ax1, ay1);
                COMP(vB2, wB2, ax2, ay2); COMP(vB3, wB3, ax3, ay3);
                k += 8;
            } else {
                COMP(vA0, wA0, ax0, ay0); COMP(vA1, wA1, ax1, ay1);
                COMP(vA2, wA2, ax2, ay2); COMP(vA3, wA3, ax3, ay3);
                k += 4;
            }
        }
        for (; k < d; ++k) {
            int c = slist[beg + k];
            float2 v = LDV(c);
            unsigned w = LDW(c);
            COMP(v, w, ax0, ay0);
        }
        float rx = (ax0 + ax1) + (ax2 + ax3);
        float ry = (ay0 + ay1) + (ay2 + ay3);
        rx = rx > 0.f ? rx : __expf(rx) - 1.f;
        ry = ry > 0.f ? ry : __expf(ry) - 1.f;
        ((float2*)out)[(unsigned)node * 64u + l] = make_float2(rx, ry);
    }
#undef LDV
#undef LDW
#undef COMP
}

extern "C" void kernel_launch(void* const* d_in, const int* in_sizes, int n_in,
                              void* d_out, int out_size, void* d_ws, size_t ws_size,
                              hipStream_t stream)
{
    const float* x  = (const float*)d_in[0];
    const float* W  = (const float*)d_in[1];
    const float* a  = (const float*)d_in[2];
    const int* esrc = (const int*)d_in[3];
    const int* edst = (const int*)d_in[4];
    const int n_nodes = in_sizes[0] / DIN;
    const int n_edges = in_sizes[3];
    float* out = (float*)d_out;

    const int nb = (n_nodes + BNODES - 1) >> BSH;

    // workspace layout (~46.5 MB)
    unsigned int* hq = (unsigned int*)d_ws;                 // [N*64] bf16 pairs, 25.6MB
    float2* usrc = (float2*)(hq + (size_t)n_nodes * 64);    // [N*4]
    float2* vdst = usrc + (size_t)n_nodes * NH;             // [N*4]
    int* gcur0  = (int*)(vdst + (size_t)n_nodes * NH);      // [MAXB]
    unsigned int* binned = (unsigned int*)(gcur0 + MAXB);   // [nb*BCAP], 17.6MB

    hipMemsetAsync(gcur0, 0, MAXB * sizeof(int), stream);

    feat_kernel<<<(n_nodes + NPBF - 1) / NPBF, 256, 0, stream>>>(
        x, W, a, hq, usrc, vdst, n_nodes);

    binscatter_kernel<<<(n_edges + EPB - 1) / EPB, 256, 0, stream>>>(
        esrc, edst, gcur0, binned, n_edges, nb);

    bucket_kernel<<<nb * 4, 512, 0, stream>>>(
        gcur0, binned, hq, usrc, vdst, out, n_nodes);
}

// Round 8
// 409.102 us; speedup vs baseline: 2.4237x; 1.0098x over previous
//
#include <hip/hip_runtime.h>
#include <hip/hip_bf16.h>

#define DIN 96
#define DOUT 32
#define NH 4
#define DTOT 128          // NH * DOUT, concat output width
#define SLOPE 0.2f
#define NPBF 64           // nodes per block in feat_kernel (4 per thread)
#define BSH 7             // bucket shift: 128 src nodes per parent bucket
#define BNODES 128
#define MAXB 1024         // max parent buckets (N <= 131072)
#define EPB 4096          // edges per scatter block
#define BCAP 5632         // fixed parent-bucket capacity (E/nb=4096 avg +24 sigma)
#define QSL  2304         // quarter wbuf capacity (avg 1024, +39 sigma)
#define SLSZ 2432         // quarter slist capacity (QSL + 32*4 pad slack)
#define GSTR 16           // gcur0 counter stride in ints (64B = one cacheline,
                          // kills the 611K-atomic/49-cacheline reserve hammer)

// pack two fp32 -> two bf16 (RNE) in one uint
__device__ __forceinline__ unsigned int packbf2(float lo, float hi) {
    unsigned int a = __float_as_uint(lo), b = __float_as_uint(hi);
    a += 0x7fffu + ((a >> 16) & 1u);
    b += 0x7fffu + ((b >> 16) & 1u);
    return (a >> 16) | (b & 0xffff0000u);
}

// ---------------------------------------------------------------------------
// feat_kernel: h[n] = x[n] @ W (all heads) -> packed bf16, plus per-node
// attention exp factors.
//   - 4 nodes/thread (64 nodes/block): 32 FMA per W-fragment read
//   - W split into Wlo/Whi planes -> ds_read_b128 at 16B stride, bank-clean
//   - v2: register prefetch of next k-block's x (T14 issue-early/consume-
//     late): global latency hides under the 128 FMAs of the current block
//   - 49.25 KB LDS -> 3 blocks/CU
// ---------------------------------------------------------------------------
__global__ __launch_bounds__(256) void feat_kernel(
    const float* __restrict__ x, const float* __restrict__ W,
    const float* __restrict__ a,
    unsigned int* __restrict__ hq,      // [N*64] packed bf16 pairs
    float2* __restrict__ usrc, float2* __restrict__ vdst,
    int n_nodes)
{
    __shared__ float Wlo[DIN * 64];     // [k][cbi*4 + jj], cols 8*cbi + jj
    __shared__ float Whi[DIN * 64];     // [k][cbi*4 + jj], cols 8*cbi + 4 + jj
    __shared__ float al[NH * 2 * DOUT];
    const int t = threadIdx.x;

    for (int i = t; i < DIN * DTOT; i += 256) {
        int k = i >> 7, c = i & 127;        // c = output col 0..127
        int head = c >> 5, j = c & 31;
        float w = W[head * (DIN * DOUT) + k * DOUT + j];
        int cbi = c >> 3, jj = c & 7;
        if (jj < 4) Wlo[(k << 6) + (cbi << 2) + jj] = w;
        else        Whi[(k << 6) + (cbi << 2) + (jj - 4)] = w;
    }
    for (int i = t; i < NH * 2 * DOUT; i += 256) al[i] = a[i];
    __syncthreads();

    const int cbi = t & 15;             // column block: cols 8*cbi .. 8*cbi+7
    const int ng = t >> 4;              // node group (4 nodes)
    const int node0 = blockIdx.x * NPBF;
    const int g0 = node0 + ng * 4;

    bool ok[4];
    const float* xp[4];
#pragma unroll
    for (int i = 0; i < 4; ++i) {
        ok[i] = (g0 + i) < n_nodes;
        xp[i] = x + (size_t)(g0 + i) * DIN;
    }

    float acc[4][8];
#pragma unroll
    for (int i = 0; i < 4; ++i)
#pragma unroll
        for (int j = 0; j < 8; ++j) acc[i][j] = 0.f;

    // prologue: load k=0 block
    float4 xv[4], xn[4];
#pragma unroll
    for (int i = 0; i < 4; ++i)
        xv[i] = ok[i] ? *(const float4*)(xp[i])
                      : make_float4(0.f, 0.f, 0.f, 0.f);

#pragma unroll 2
    for (int k = 0; k < DIN; k += 4) {
        const bool pf = (k + 4 < DIN);
#pragma unroll
        for (int i = 0; i < 4; ++i)
            xn[i] = (pf && ok[i]) ? *(const float4*)(xp[i] + k + 4)
                                  : make_float4(0.f, 0.f, 0.f, 0.f);
#pragma unroll
        for (int kk = 0; kk < 4; ++kk) {
            const float4 wlo = *(const float4*)&Wlo[((k + kk) << 6) + (cbi << 2)];
            const float4 whi = *(const float4*)&Whi[((k + kk) << 6) + (cbi << 2)];
#pragma unroll
            for (int i = 0; i < 4; ++i) {
                const float xvv = (kk == 0) ? xv[i].x : (kk == 1) ? xv[i].y
                                 : (kk == 2) ? xv[i].z : xv[i].w;
                acc[i][0] = fmaf(xvv, wlo.x, acc[i][0]);
                acc[i][1] = fmaf(xvv, wlo.y, acc[i][1]);
                acc[i][2] = fmaf(xvv, wlo.z, acc[i][2]);
                acc[i][3] = fmaf(xvv, wlo.w, acc[i][3]);
                acc[i][4] = fmaf(xvv, whi.x, acc[i][4]);
                acc[i][5] = fmaf(xvv, whi.y, acc[i][5]);
                acc[i][6] = fmaf(xvv, whi.z, acc[i][6]);
                acc[i][7] = fmaf(xvv, whi.w, acc[i][7]);
            }
        }
#pragma unroll
        for (int i = 0; i < 4; ++i) xv[i] = xn[i];
    }

    const int head = cbi >> 2;
    const int j0 = (cbi & 3) << 3;
#pragma unroll
    for (int i = 0; i < 4; ++i) {
        float ps = 0.f, pd = 0.f;
#pragma unroll
        for (int j = 0; j < 8; ++j) {
            ps += acc[i][j] * al[head * 64 + j0 + j];
            pd += acc[i][j] * al[head * 64 + 32 + j0 + j];
        }
        ps += __shfl_xor(ps, 1); ps += __shfl_xor(ps, 2);
        pd += __shfl_xor(pd, 1); pd += __shfl_xor(pd, 2);
        const int g = g0 + i;
        if (ok[i]) {
            uint4 pk;
            pk.x = packbf2(acc[i][0], acc[i][1]);
            pk.y = packbf2(acc[i][2], acc[i][3]);
            pk.z = packbf2(acc[i][4], acc[i][5]);
            pk.w = packbf2(acc[i][6], acc[i][7]);
            *(uint4*)&hq[(size_t)g * 64 + (cbi << 2)] = pk;
            if ((cbi & 3) == 0) {
                usrc[g * NH + head] = make_float2(__expf(-ps), __expf(-SLOPE * ps));
                vdst[g * NH + head] = make_float2(__expf(-pd), __expf(-SLOPE * pd));
            }
        }
    }
}

// ---------------------------------------------------------------------------
// binscatter: scatter edges (packed srcl|dst) into fixed-capacity parent-
// bucket regions. 16 edges/thread reg-staged, LDS hist, run reservation via
// atomicAdd on CACHELINE-PADDED gcur0 (GSTR): the reserve phase's ~611K
// device atomics now spread over 782 cachelines instead of 49.
// Final gcur0[b*GSTR] == bucket count.
// ---------------------------------------------------------------------------
__global__ __launch_bounds__(256) void binscatter_kernel(
    const int* __restrict__ esrc, const int* __restrict__ edst,
    int* __restrict__ gcur0, unsigned int* __restrict__ binned,
    int n_edges, int nb)
{
    __shared__ int bc[MAXB];
    const int t = threadIdx.x;
    for (int i = t; i < nb; i += 256) bc[i] = 0;
    __syncthreads();

    const int base = blockIdx.x * EPB;
    const int end = min(base + EPB, n_edges);
    const bool full = (end - base) == EPB;

    int se[16], de[16];
    if (full) {
        const int4* s4p = (const int4*)(esrc + base);
        const int4* d4p = (const int4*)(edst + base);
#pragma unroll
        for (int j = 0; j < 4; ++j) {
            int4 s4 = s4p[j * 256 + t];
            int4 d4 = d4p[j * 256 + t];
            se[j * 4 + 0] = s4.x; se[j * 4 + 1] = s4.y;
            se[j * 4 + 2] = s4.z; se[j * 4 + 3] = s4.w;
            de[j * 4 + 0] = d4.x; de[j * 4 + 1] = d4.y;
            de[j * 4 + 2] = d4.z; de[j * 4 + 3] = d4.w;
        }
#pragma unroll
        for (int j = 0; j < 16; ++j)
            atomicAdd(&bc[se[j] >> BSH], 1);
    } else {
#pragma unroll
        for (int j = 0; j < 16; ++j) {
            const int e = base + j * 256 + t;
            se[j] = (e < end) ? esrc[e] : 0;
            de[j] = (e < end) ? edst[e] : 0;
            if (e < end) atomicAdd(&bc[se[j] >> BSH], 1);
        }
    }
    __syncthreads();

    for (int i = t; i < nb; i += 256) {
        int c = bc[i];
        bc[i] = (c > 0) ? (i * BCAP + atomicAdd(&gcur0[i * GSTR], c)) : 0;
    }
    __syncthreads();

    if (full) {
#pragma unroll
        for (int j = 0; j < 16; ++j) {
            int s = se[j];
            int pos = atomicAdd(&bc[s >> BSH], 1);
            binned[pos] = ((unsigned int)(s & (BNODES - 1)) << 17) | (unsigned int)de[j];
        }
    } else {
#pragma unroll
        for (int j = 0; j < 16; ++j) {
            const int e = base + j * 256 + t;
            if (e < end) {
                int s = se[j];
                int pos = atomicAdd(&bc[s >> BSH], 1);
                binned[pos] = ((unsigned int)(s & (BNODES - 1)) << 17) | (unsigned int)de[j];
            }
        }
    }
}

// ---------------------------------------------------------------------------
// bucket_kernel: 4 quarter-blocks per parent bucket. Block (p,q) owns the 32
// nodes [p*128 + q*32, +32). One filtered pass over the parent's binned words
// -> compact LDS wbuf + hist; 32-entry scan; LDS fine-sort into slist; then
// the proven register-pipeline gather. ~19.3 KB LDS, 3128 blocks -> ~3
// scheduling rounds, dynamic balancing. (R7: 164 us, at the gather ceiling.)
// ---------------------------------------------------------------------------
__global__ __launch_bounds__(512) void bucket_kernel(
    const int* __restrict__ gcur0,
    const unsigned int* __restrict__ binned,
    const unsigned int* __restrict__ hv,    // [N*64] packed bf16 pairs
    const float2* __restrict__ usrc, const float2* __restrict__ vdst,
    float* __restrict__ out, int n_nodes)
{
    __shared__ unsigned int wbuf[QSL];
    __shared__ __align__(16) int slist[SLSZ];
    __shared__ int dcnt[32];
    __shared__ int sc[32];
    __shared__ int dcur[32];
    __shared__ int qn_s;
    const int t = threadIdx.x;
    const int p = (int)blockIdx.x >> 2;
    const int q = (int)blockIdx.x & 3;
    const unsigned pbase = (unsigned)p * BCAP;
    int cnt = gcur0[p * GSTR];
    if (cnt > BCAP - 512) cnt = BCAP - 512;   // safety clamp (never triggers)
    const int node0 = (p << BSH) + (q << 5);

    if (t < 32) dcnt[t] = 0;
    if (t == 0) qn_s = 0;
    __syncthreads();

    // single filtered pass: compact quarter's words into wbuf + histogram
    for (int i = t; i < cnt; i += 512) {
        unsigned int w = binned[pbase + i];
        int s = (int)(w >> 17);
        if ((s >> 5) == q) {
            int pos = atomicAdd(&qn_s, 1);
            if (pos < QSL) {
                wbuf[pos] = w;
                atomicAdd(&dcnt[s & 31], 1);
            }
        }
    }
    __syncthreads();
    int qn = qn_s; if (qn > QSL) qn = QSL;

    int pd = 0;
    if (t < 32) { pd = (dcnt[t] + 3) & ~3; sc[t] = pd; }
    __syncthreads();
    for (int off = 1; off < 32; off <<= 1) {
        int v = 0;
        if (t < 32 && t >= off) v = sc[t - off];
        __syncthreads();
        if (t < 32) sc[t] += v;
        __syncthreads();
    }
    if (t < 32) dcur[t] = sc[t] - pd;     // local 4-aligned start
    __syncthreads();
    for (int i = t; i < qn; i += 512) {
        unsigned int w = wbuf[i];
        int pos = atomicAdd(&dcur[(w >> 17) & 31], 1);
        slist[pos] = (int)(w & 0x1ffffu);
    }
    __syncthreads();
    // dcur[n] is now start+deg, so start = dcur[n] - dcnt[n]

    // ------------------------- gather phase -------------------------
    const int l = t & 63;          // cols {2l, 2l+1}
    const int head = l >> 4;
    const unsigned loff = (unsigned)l << 2;     // byte offset in hv row (256B)
    const unsigned hoff = (unsigned)head << 3;  // byte offset in vdst row (32B)
    const char* __restrict__ hvb = (const char*)hv;
    const char* __restrict__ vdb = (const char*)vdst;
    const int sub = t >> 6;        // wave id 0..7 (uniform per wave)

#define LDV(c) (*(const float2*)(vdb + ((((unsigned)(c)) << 5) + hoff)))
#define LDW(c) (*(const unsigned int*)(hvb + ((((unsigned)(c)) << 8) + loff)))
#define COMP(vv, ww, AX, AY) do {                                   \
        float e_ = fminf(u.x * (vv).x, u.y * (vv).y);               \
        AX = fmaf(e_, __uint_as_float((ww) << 16), AX);             \
        AY = fmaf(e_, __uint_as_float((ww) & 0xffff0000u), AY);     \
    } while (0)

    for (int r = 0; r < 4; ++r) {
        const int nd = r * 8 + sub;
        const int node = node0 + nd;
        if (node >= n_nodes) break;           // wave-uniform exit
        const int d = dcnt[nd];
        const int beg = dcur[nd] - d;         // local, multiple of 4
        const float2 u = usrc[(unsigned)node * 4u + head];

        float ax0 = 0.f, ay0 = 0.f, ax1 = 0.f, ay1 = 0.f;
        float ax2 = 0.f, ay2 = 0.f, ax3 = 0.f, ay3 = 0.f;
        int k = 0;
        if (d >= 4) {
            int4 cA = *(const int4*)&slist[beg];
            float2 vA0 = LDV(cA.x), vA1 = LDV(cA.y), vA2 = LDV(cA.z), vA3 = LDV(cA.w);
            unsigned wA0 = LDW(cA.x), wA1 = LDW(cA.y), wA2 = LDW(cA.z), wA3 = LDW(cA.w);

            for (; k + 12 <= d; k += 8) {
                int4 cB = *(const int4*)&slist[beg + k + 4];
                float2 vB0 = LDV(cB.x), vB1 = LDV(cB.y), vB2 = LDV(cB.z), vB3 = LDV(cB.w);
                unsigned wB0 = LDW(cB.x), wB1 = LDW(cB.y), wB2 = LDW(cB.z), wB3 = LDW(cB.w);
                COMP(vA0, wA0, ax0, ay0); COMP(vA1, wA1, ax1, ay1);
                COMP(vA2, wA2, ax2, ay2); COMP(vA3, wA3, ax3, ay3);
                int4 cN = *(const int4*)&slist[beg + k + 8];
                vA0 = LDV(cN.x); vA1 = LDV(cN.y); vA2 = LDV(cN.z); vA3 = LDV(cN.w);
                wA0 = LDW(cN.x); wA1 = LDW(cN.y); wA2 = LDW(cN.z); wA3 = LDW(cN.w);
                COMP(vB0, wB0, ax0, ay0); COMP(vB1, wB1, ax1, ay1);
                COMP(vB2, wB2, ax2, ay2); COMP(vB3, wB3, ax3, ay3);
            }
            if (k + 8 <= d) {
                int4 cB = *(const int4*)&slist[beg + k + 4];
                float2 vB0 = LDV(cB.x), vB1 = LDV(cB.y), vB2 = LDV(cB.z), vB3 = LDV(cB.w);
                unsigned wB0 = LDW(cB.x), wB1 = LDW(cB.y), wB2 = LDW(cB.z), wB3 = LDW(cB.w);
                COMP(vA0, wA0, ax0, ay0); COMP(vA1, wA1, ax1, ay1);
                COMP(vA2, wA2, ax2, ay2); COMP(vA3, wA3, ax3, ay3);
                COMP(vB0, wB0, ax0, ay0); COMP(vB1, wB1, ax1, ay1);
                COMP(vB2, wB2, ax2, ay2); COMP(vB3, wB3, ax3, ay3);
                k += 8;
            } else {
                COMP(vA0, wA0, ax0, ay0); COMP(vA1, wA1, ax1, ay1);
                COMP(vA2, wA2, ax2, ay2); COMP(vA3, wA3, ax3, ay3);
                k += 4;
            }
        }
        for (; k < d; ++k) {
            int c = slist[beg + k];
            float2 v = LDV(c);
            unsigned w = LDW(c);
            COMP(v, w, ax0, ay0);
        }
        float rx = (ax0 + ax1) + (ax2 + ax3);
        float ry = (ay0 + ay1) + (ay2 + ay3);
        rx = rx > 0.f ? rx : __expf(rx) - 1.f;
        ry = ry > 0.f ? ry : __expf(ry) - 1.f;
        ((float2*)out)[(unsigned)node * 64u + l] = make_float2(rx, ry);
    }
#undef LDV
#undef LDW
#undef COMP
}

extern "C" void kernel_launch(void* const* d_in, const int* in_sizes, int n_in,
                              void* d_out, int out_size, void* d_ws, size_t ws_size,
                              hipStream_t stream)
{
    const float* x  = (const float*)d_in[0];
    const float* W  = (const float*)d_in[1];
    const float* a  = (const float*)d_in[2];
    const int* esrc = (const int*)d_in[3];
    const int* edst = (const int*)d_in[4];
    const int n_nodes = in_sizes[0] / DIN;
    const int n_edges = in_sizes[3];
    float* out = (float*)d_out;

    const int nb = (n_nodes + BNODES - 1) >> BSH;

    // workspace layout (~46.6 MB)
    unsigned int* hq = (unsigned int*)d_ws;                 // [N*64] bf16 pairs, 25.6MB
    float2* usrc = (float2*)(hq + (size_t)n_nodes * 64);    // [N*4]
    float2* vdst = usrc + (size_t)n_nodes * NH;             // [N*4]
    int* gcur0  = (int*)(vdst + (size_t)n_nodes * NH);      // [MAXB*GSTR], 64KB
    unsigned int* binned = (unsigned int*)(gcur0 + MAXB * GSTR); // [nb*BCAP], 17.6MB

    hipMemsetAsync(gcur0, 0, MAXB * GSTR * sizeof(int), stream);

    feat_kernel<<<(n_nodes + NPBF - 1) / NPBF, 256, 0, stream>>>(
        x, W, a, hq, usrc, vdst, n_nodes);

    binscatter_kernel<<<(n_edges + EPB - 1) / EPB, 256, 0, stream>>>(
        esrc, edst, gcur0, binned, n_edges, nb);

    bucket_kernel<<<nb * 4, 512, 0, stream>>>(
        gcur0, binned, hq, usrc, vdst, out, n_nodes);
}